// Round 14
// baseline (214.657 us; speedup 1.0000x reference)
//
#include <hip/hip_runtime.h>
#include <hip/hip_bf16.h>
#include <cstdint>
#include <cstddef>

#define B_ 8
#define N_ 4096
#define DIM_ 768
#define H_ 12
#define M_ (B_*N_)        // 32768
#define SCALE_ 0.125f
#define NS2 16
#define KDIM 768
#define NKT 12
#define NITER 6

typedef __attribute__((ext_vector_type(8))) short s8v;
typedef __attribute__((ext_vector_type(4))) float f4v;

__device__ inline float bf2f(unsigned short u) {
    unsigned v = ((unsigned)u) << 16;
    return __builtin_bit_cast(float, v);
}
__device__ inline unsigned short f2bf(float f) {
    unsigned u = __builtin_bit_cast(unsigned, f);
    return (unsigned short)((u + 0x7FFFu + ((u >> 16) & 1u)) >> 16);
}
__device__ inline void gload16(const void* g, void* l) {
    __builtin_amdgcn_global_load_lds(
        (const __attribute__((address_space(1))) void*)g,
        (__attribute__((address_space(3))) void*)l, 16, 0, 0);
}

#define BARX() __builtin_amdgcn_s_barrier()
#define PRIO1() __builtin_amdgcn_s_setprio(1)
#define PRIO0() __builtin_amdgcn_s_setprio(0)
#define VM4() asm volatile("s_waitcnt vmcnt(4)" ::: "memory")
#define VM0() asm volatile("s_waitcnt vmcnt(0)" ::: "memory")

// ---------------- 256x256 8-phase bf16 GEMM + fused alpha score/wsum column ----------
// tn<3 : k GEMM (B = Wk rows tn*256..), store bf16 to kb[row*768 + tn*256 + c].
// tn==3: score block: scores = x@avec^T (MFMA), block softmax, P = E^T X (MFMA),
//        emits pv1[(b*16+slice)*12+h][768] (unnormalized Σ e·x) and pms1[bh][slice]{m,s}.
__global__ __launch_bounds__(512, 2)
void gemm8(const unsigned short* __restrict__ A, int ldaE,
           const unsigned short* __restrict__ Bmat,
           unsigned short* __restrict__ Cb,
           const unsigned short* __restrict__ avecb,
           float* __restrict__ pv1, float* __restrict__ pms1,
           int ntn)
{
    __shared__ __align__(16) char smem[131072];   // 2 bufs x 4 regions x 16KB
    const int tid = threadIdx.x;
    const int l = tid & 63, w = tid >> 6;
    const int lr = l & 15, g = l >> 4;
    const int wm = w >> 2, wn = w & 3;

    const int nwg = gridDim.x, cpx = nwg >> 3;
    const int bid = blockIdx.x;
    const int lg = (bid & 7) * cpx + (bid >> 3);
    const int tm = lg / ntn, tn = lg % ntn;
    const int m0 = tm * 256, n0 = tn * 256;

    const long ldaB = (long)ldaE * 2;
    const long ldbB = (long)KDIM * 2;

    const int srA = w * 8 + (l >> 3);
    const int kbs = (l & 7) * 16;
    const int kbx = kbs ^ ((srA & 7) << 4);
    long offA[2], offB[2];
    offA[0] = (long)(srA) * ldaB + kbx;
    offA[1] = (long)(128 + srA) * ldaB + kbx;
    offB[0] = (long)(((srA >> 5)) * 64 + (srA & 31)) * ldbB + kbx;
    offB[1] = (long)((2 + (srA >> 5)) * 64 + (srA & 31)) * ldbB + kbx;

    const char* Abase = (const char*)(A + (size_t)m0 * ldaE);
    const char* Bbase = (const char*)(Bmat + (size_t)n0 * KDIM);

    const int aoff = (wm * 64 + lr) * 128;
    const int boff = (wn * 32 + lr) * 128;
    const int kx0 = (g * 16) ^ ((lr & 7) << 4);
    const int kx1 = (64 + g * 16) ^ ((lr & 7) << 4);

#define STG_A(buf_, qm_, kt_) { \
    const char* s0_ = Abase + (long)(kt_) * 2 + (long)(qm_) * 64 * ldaB; \
    char* d0_ = smem + ((buf_) * 4 + (qm_)) * 16384 + w * 1024; \
    gload16(s0_ + offA[0], d0_); \
    gload16(s0_ + offA[1], d0_ + 8192); }

#define STG_B(buf_, qn_, kt_) { \
    const char* s0_ = Bbase + (long)(kt_) * 2 + (long)(qn_) * 32 * ldbB; \
    char* d0_ = smem + ((buf_) * 4 + 2 + (qn_)) * 16384 + w * 1024; \
    gload16(s0_ + offB[0], d0_); \
    gload16(s0_ + offB[1], d0_ + 8192); }

    if (tn < 3) {
        // ======================= k GEMM (proven path) =======================
        f4v acc[8][4] = {};
        s8v af[4][2];
        s8v bfr[2][2][2];

#define DS_A(buf_, qm_) { \
    const char* ba_ = smem + ((buf_) * 4 + (qm_)) * 16384 + aoff; \
    af[0][0] = *(const s8v*)(ba_ +    0 + kx0); af[0][1] = *(const s8v*)(ba_ +    0 + kx1); \
    af[1][0] = *(const s8v*)(ba_ + 2048 + kx0); af[1][1] = *(const s8v*)(ba_ + 2048 + kx1); \
    af[2][0] = *(const s8v*)(ba_ + 4096 + kx0); af[2][1] = *(const s8v*)(ba_ + 4096 + kx1); \
    af[3][0] = *(const s8v*)(ba_ + 6144 + kx0); af[3][1] = *(const s8v*)(ba_ + 6144 + kx1); }

#define DS_B(buf_, qn_) { \
    const char* bb_ = smem + ((buf_) * 4 + 2 + (qn_)) * 16384 + boff; \
    bfr[qn_][0][0] = *(const s8v*)(bb_ +    0 + kx0); bfr[qn_][0][1] = *(const s8v*)(bb_ +    0 + kx1); \
    bfr[qn_][1][0] = *(const s8v*)(bb_ + 2048 + kx0); bfr[qn_][1][1] = *(const s8v*)(bb_ + 2048 + kx1); }

#define MM(fmg_, fng_, qn_, kk_) \
    acc[fmg_][fng_] = __builtin_amdgcn_mfma_f32_16x16x32_bf16(af[(fmg_)&3][kk_], bfr[qn_][(fng_)&1][kk_], acc[fmg_][fng_], 0, 0, 0);

#define MFMA8(qm_, qn_, kk_) \
    MM((qm_)*4+0, (qn_)*2+0, qn_, kk_) MM((qm_)*4+0, (qn_)*2+1, qn_, kk_) \
    MM((qm_)*4+1, (qn_)*2+0, qn_, kk_) MM((qm_)*4+1, (qn_)*2+1, qn_, kk_) \
    MM((qm_)*4+2, (qn_)*2+0, qn_, kk_) MM((qm_)*4+2, (qn_)*2+1, qn_, kk_) \
    MM((qm_)*4+3, (qn_)*2+0, qn_, kk_) MM((qm_)*4+3, (qn_)*2+1, qn_, kk_)

#define MFMA16(qm_, qn_) { MFMA8(qm_, qn_, 0) MFMA8(qm_, qn_, 1) }

        STG_A(0, 0, 0); STG_B(0, 0, 0); STG_A(0, 1, 0); STG_B(0, 1, 0);
        STG_A(1, 0, 64); STG_B(1, 0, 64);
        VM4(); BARX();

        for (int i = 0; i < NITER; ++i) {
            const int t1k = (2 * i + 1) * 64, t2k = (2 * i + 2) * 64, t3k = (2 * i + 3) * 64;
            const bool h2 = (2 * i + 2) < NKT, h3 = (2 * i + 3) < NKT;
            const bool last = (i == NITER - 1);
            DS_A(0, 0); DS_B(0, 0); STG_B(1, 1, t1k);
            BARX(); PRIO1(); MFMA16(0, 0); PRIO0(); BARX();
            DS_B(0, 1); STG_A(1, 1, t1k);
            BARX(); PRIO1(); MFMA16(0, 1); PRIO0(); BARX();
            DS_A(0, 1); if (h2) STG_A(0, 0, t2k);
            BARX(); PRIO1(); MFMA16(1, 0); PRIO0(); BARX();
            if (h2) STG_B(0, 0, t2k);
            BARX(); PRIO1(); MFMA16(1, 1); PRIO0();
            if (last) { VM0(); } else { VM4(); }
            BARX();
            DS_A(1, 0); DS_B(1, 0); if (h2) STG_A(0, 1, t2k);
            BARX(); PRIO1(); MFMA16(0, 0); PRIO0(); BARX();
            DS_B(1, 1); if (h2) STG_B(0, 1, t2k);
            BARX(); PRIO1(); MFMA16(0, 1); PRIO0(); BARX();
            DS_A(1, 1); if (h3) STG_A(1, 0, t3k);
            BARX(); PRIO1(); MFMA16(1, 0); PRIO0(); BARX();
            if (h3) STG_B(1, 0, t3k);
            BARX(); PRIO1(); MFMA16(1, 1); PRIO0();
            if (last) { VM0(); } else { VM4(); }
            BARX();
        }

        const int c0 = tn * 256;
#pragma unroll
        for (int fmg = 0; fmg < 8; ++fmg) {
#pragma unroll
            for (int fng = 0; fng < 4; ++fng) {
                const int col = c0 + wn * 64 + fng * 16 + lr;
#pragma unroll
                for (int r = 0; r < 4; ++r) {
                    const int row = m0 + wm * 128 + fmg * 16 + g * 4 + r;
                    Cb[(size_t)row * DIM_ + col] = f2bf(acc[fmg][fng][r]);
                }
            }
        }
#undef DS_A
#undef DS_B
#undef MM
#undef MFMA8
#undef MFMA16
    } else {
        // ======================= score block =======================
        const int b = m0 >> 12;
        const int slice = (m0 & (N_ - 1)) >> 8;      // 0..15
        // LDS map: A regions (buf*4+qm)*16384 (+hi*8192); avec at 32768+kt*2048;
        //          ET at 98304 ([16][272] bf16, stride 544B); Lm 107008; Ls 107520.
        // stage avec (waves 0,1; pre-swizzled source, linear dst)
        if (w < 2) {
            const int rw = l >> 3;
            const int by = ((l & 7) * 16) ^ (rw << 4);
#pragma unroll
            for (int k6 = 0; k6 < 6; ++k6) {
                const int kt = w * 6 + k6;
                gload16((const char*)avecb + (size_t)rw * 1536 + kt * 128 + by,
                        smem + 32768 + kt * 2048);
                gload16((const char*)avecb + (size_t)(8 + rw) * 1536 + kt * 128 + by,
                        smem + 32768 + kt * 2048 + 1024);
            }
        }
        STG_A(0, 0, 0); STG_A(0, 1, 0);
        STG_A(1, 0, 64); STG_A(1, 1, 64);
        VM4(); BARX();

        // phase 1: scores = x @ avec^T, acc per wave: rows w*32 + j*16
        f4v sacc[2] = {};
        for (int kt = 0; kt < 12; ++kt) {
            const int buf = kt & 1;
#pragma unroll
            for (int j = 0; j < 2; ++j) {
                const int r0 = w * 32 + j * 16;
                const int qm = (r0 >> 6) & 1, hi = r0 >> 7, loc = r0 & 63;
                const char* ab = smem + (buf * 4 + qm) * 16384 + hi * 8192 + (loc + lr) * 128;
                s8v a0 = *(const s8v*)(ab + kx0);
                s8v a1 = *(const s8v*)(ab + kx1);
                const char* vb = smem + 32768 + kt * 2048 + lr * 128;
                s8v b0 = *(const s8v*)(vb + kx0);
                s8v b1 = *(const s8v*)(vb + kx1);
                sacc[j] = __builtin_amdgcn_mfma_f32_16x16x32_bf16(a0, b0, sacc[j], 0, 0, 0);
                sacc[j] = __builtin_amdgcn_mfma_f32_16x16x32_bf16(a1, b1, sacc[j], 0, 0, 0);
            }
            BARX();
            if (kt + 2 < 12) {
                const int kk2 = (kt + 2) * 64;
                STG_A(buf, 0, kk2); STG_A(buf, 1, kk2);
            }
            if (kt <= 9) { VM4(); } else { VM0(); }
            BARX();
        }

        // softmax per head (col lr), rows of this block
        float dd[8];
#pragma unroll
        for (int j = 0; j < 2; ++j)
#pragma unroll
            for (int r = 0; r < 4; ++r) dd[j * 4 + r] = sacc[j][r] * SCALE_;

        float mw = dd[0];
#pragma unroll
        for (int q2 = 1; q2 < 8; ++q2) mw = fmaxf(mw, dd[q2]);
        mw = fmaxf(mw, __shfl_xor(mw, 16));
        mw = fmaxf(mw, __shfl_xor(mw, 32));
        float* Lm = (float*)(smem + 107008);
        float* Ls = (float*)(smem + 107520);
        if (l < 16) Lm[w * 16 + lr] = mw;
        __syncthreads();
        float mfin = Lm[lr];
#pragma unroll
        for (int w2 = 1; w2 < 8; ++w2) mfin = fmaxf(mfin, Lm[w2 * 16 + lr]);

        float ss = 0.f;
#pragma unroll
        for (int j = 0; j < 2; ++j)
#pragma unroll
            for (int r = 0; r < 4; ++r) {
                const float e = __expf(dd[j * 4 + r] - mfin);
                ss += e;
                const int row = w * 32 + j * 16 + g * 4 + r;
                *(unsigned short*)(smem + 98304 + lr * 544 + row * 2) = f2bf(e);
            }
        ss += __shfl_xor(ss, 16);
        ss += __shfl_xor(ss, 32);
        if (l < 16) Ls[w * 16 + lr] = ss;
        __syncthreads();

        if (tid < 12) {
            float S = 0.f;
#pragma unroll
            for (int w2 = 0; w2 < 8; ++w2) S += Ls[w2 * 16 + tid];
            float M2 = Lm[tid];
#pragma unroll
            for (int w2 = 1; w2 < 8; ++w2) M2 = fmaxf(M2, Lm[w2 * 16 + tid]);
            pms1[((size_t)(b * H_ + tid) * 16 + slice) * 2 + 0] = M2;
            pms1[((size_t)(b * H_ + tid) * 16 + slice) * 2 + 1] = S;
        }
        __syncthreads();

        // phase 2: P[h][d] = sum_n E[n][h] x[n][d]  (restage x, MFMA A=E^T B=X)
        for (int it = 0; it < 6; ++it) {
            const int ktA = it * 2, ktB = it * 2 + 1;
            STG_A(0, 0, ktA * 64); STG_A(0, 1, ktA * 64);
            STG_A(1, 0, ktB * 64); STG_A(1, 1, ktB * 64);
            VM0(); BARX();
            const int buf = w >> 2;
            const int kt = it * 2 + buf;
            const int d0 = (w & 3) * 16;
            const int dby = (d0 + (l & 15)) * 2;
            f4v pacc = {};
#pragma unroll
            for (int c = 0; c < 8; ++c) {
                s8v ae = *(const s8v*)(smem + 98304 + (l & 15) * 544
                                       + (c * 32 + (l >> 4) * 8) * 2);
                const char* xr = smem + (buf * 4 + ((c >> 1) & 1)) * 16384 + (c >> 2) * 8192;
                const int nb = (c & 1) * 32 + (l >> 4) * 8;
                s8v bx;
#pragma unroll
                for (int j = 0; j < 8; ++j)
                    bx[j] = (short)*(const unsigned short*)(xr + (nb + j) * 128 + (dby ^ (j << 4)));
                pacc = __builtin_amdgcn_mfma_f32_16x16x32_bf16(ae, bx, pacc, 0, 0, 0);
            }
            if ((l >> 4) < 3) {
#pragma unroll
                for (int r = 0; r < 4; ++r) {
                    const int h = (l >> 4) * 4 + r;
                    pv1[((size_t)(b * 16 + slice) * 12 + h) * 768
                        + kt * 64 + d0 + (l & 15)] = pacc[r];
                }
            }
            BARX();
        }
    }
#undef STG_A
#undef STG_B
}

// ---------------- 128x256 4-phase bf16 GEMM (unchanged, proven) ----------------
template<int MODE>
__global__ __launch_bounds__(512, 2)
void gemm128(const unsigned short* __restrict__ A, int ldaE,
             const unsigned short* __restrict__ Bmat,
             float* __restrict__ Cf, unsigned short* __restrict__ CbO,
             const float* __restrict__ bias, const float* __restrict__ addW,
             int Nc, int ntn)
{
    __shared__ __align__(16) char smem[98304];
    const int tid = threadIdx.x;
    const int l = tid & 63, w = tid >> 6;
    const int lr = l & 15, g = l >> 4;
    const int wm = w >> 2, wn = w & 3;

    const int nwg = gridDim.x, cpx = nwg >> 3;
    const int bid = blockIdx.x;
    const int lg = (bid & 7) * cpx + (bid >> 3);
    const int tm = lg / ntn, tn = lg % ntn;
    const int m0 = tm * 128, n0 = tn * 256;

    const long ldaB = (long)ldaE * 2;
    const long ldbB = (long)KDIM * 2;

    const unsigned short* Bp = Bmat;
    if (MODE == 0) Bp = Bmat + (size_t)(m0 >> 12) * (DIM_ * DIM_);

    const int srA = w * 8 + (l >> 3);
    const int kbs = (l & 7) * 16;
    const int kbx = kbs ^ ((srA & 7) << 4);
    long offA[2], offB[2];
    offA[0] = (long)(srA) * ldaB + kbx;
    offA[1] = (long)(64 + srA) * ldaB + kbx;
    offB[0] = (long)(((srA >> 5)) * 64 + (srA & 31)) * ldbB + kbx;
    offB[1] = (long)((2 + (srA >> 5)) * 64 + (srA & 31)) * ldbB + kbx;

    const char* Abase = (const char*)(A + (size_t)m0 * ldaE);
    const char* Bbase = (const char*)(Bp + (size_t)n0 * KDIM);

    const int aoff = (wm * 64 + lr) * 128;
    const int boff = (wn * 32 + lr) * 128;
    const int kx0 = (g * 16) ^ ((lr & 7) << 4);
    const int kx1 = (64 + g * 16) ^ ((lr & 7) << 4);

    f4v acc[4][4] = {};
    s8v af[4][2];
    s8v bfr[2][2][2];

#define STG_A1(buf_, kt_) { \
    const char* s0_ = Abase + (long)(kt_) * 2; \
    char* d0_ = smem + ((buf_) * 3) * 16384 + w * 1024; \
    gload16(s0_ + offA[0], d0_); \
    gload16(s0_ + offA[1], d0_ + 8192); }

#define STG_B1(buf_, qn_, kt_) { \
    const char* s0_ = Bbase + (long)(kt_) * 2 + (long)(qn_) * 32 * ldbB; \
    char* d0_ = smem + ((buf_) * 3 + 1 + (qn_)) * 16384 + w * 1024; \
    gload16(s0_ + offB[0], d0_); \
    gload16(s0_ + offB[1], d0_ + 8192); }

#define DS_A1(buf_) { \
    const char* ba_ = smem + ((buf_) * 3) * 16384 + aoff; \
    af[0][0] = *(const s8v*)(ba_ +    0 + kx0); af[0][1] = *(const s8v*)(ba_ +    0 + kx1); \
    af[1][0] = *(const s8v*)(ba_ + 2048 + kx0); af[1][1] = *(const s8v*)(ba_ + 2048 + kx1); \
    af[2][0] = *(const s8v*)(ba_ + 4096 + kx0); af[2][1] = *(const s8v*)(ba_ + 4096 + kx1); \
    af[3][0] = *(const s8v*)(ba_ + 6144 + kx0); af[3][1] = *(const s8v*)(ba_ + 6144 + kx1); }

#define DS_B1(buf_, qn_) { \
    const char* bb_ = smem + ((buf_) * 3 + 1 + (qn_)) * 16384 + boff; \
    bfr[qn_][0][0] = *(const s8v*)(bb_ +    0 + kx0); bfr[qn_][0][1] = *(const s8v*)(bb_ +    0 + kx1); \
    bfr[qn_][1][0] = *(const s8v*)(bb_ + 2048 + kx0); bfr[qn_][1][1] = *(const s8v*)(bb_ + 2048 + kx1); }

#define MM1(fm_, fng_, qn_, kk_) \
    acc[fm_][fng_] = __builtin_amdgcn_mfma_f32_16x16x32_bf16(af[fm_][kk_], bfr[qn_][(fng_)&1][kk_], acc[fm_][fng_], 0, 0, 0);

#define MFMA16_1(qn_, kk_) \
    MM1(0, (qn_)*2+0, qn_, kk_) MM1(0, (qn_)*2+1, qn_, kk_) \
    MM1(1, (qn_)*2+0, qn_, kk_) MM1(1, (qn_)*2+1, qn_, kk_) \
    MM1(2, (qn_)*2+0, qn_, kk_) MM1(2, (qn_)*2+1, qn_, kk_) \
    MM1(3, (qn_)*2+0, qn_, kk_) MM1(3, (qn_)*2+1, qn_, kk_)

#define MFMA32_1(qn_) { MFMA16_1(qn_, 0) MFMA16_1(qn_, 1) }

    STG_A1(0, 0); STG_B1(0, 0, 0); STG_B1(0, 1, 0);
    STG_A1(1, 64); STG_B1(1, 0, 64);
    VM4(); BARX();

    for (int i = 0; i < NITER; ++i) {
        const int t1k = (2 * i + 1) * 64, t2k = (2 * i + 2) * 64, t3k = (2 * i + 3) * 64;
        const bool h2 = (2 * i + 2) < NKT, h3 = (2 * i + 3) < NKT;
        const bool last = (i == NITER - 1);
        DS_A1(0); DS_B1(0, 0); STG_B1(1, 1, t1k);
        BARX(); PRIO1(); MFMA32_1(0); PRIO0(); BARX();
        DS_B1(0, 1); if (h2) { STG_A1(0, t2k); STG_B1(0, 0, t2k); }
        BARX(); PRIO1(); MFMA32_1(1); PRIO0();
        if (last) { VM0(); } else { VM4(); }
        BARX();
        DS_A1(1); DS_B1(1, 0); if (h2) STG_B1(0, 1, t2k);
        BARX(); PRIO1(); MFMA32_1(0); PRIO0(); BARX();
        DS_B1(1, 1); if (h3) { STG_A1(1, t3k); STG_B1(1, 0, t3k); }
        BARX(); PRIO1(); MFMA32_1(1); PRIO0();
        if (last) { VM0(); } else { VM4(); }
        BARX();
    }

    const int jb = m0 % DIM_;   // row offset within batch (MODE 1)
#pragma unroll
    for (int fm = 0; fm < 4; ++fm) {
#pragma unroll
        for (int fng = 0; fng < 4; ++fng) {
            const int col = n0 + wn * 64 + fng * 16 + lr;
#pragma unroll
            for (int r = 0; r < 4; ++r) {
                const int ro = wm * 64 + fm * 16 + g * 4 + r;
                const int row = m0 + ro;
                if (MODE == 0) {
                    Cf[(size_t)row * Nc + col] = acc[fm][fng][r] + bias[col];
                } else {
                    CbO[(size_t)row * Nc + col] =
                        f2bf(acc[fm][fng][r] + addW[(size_t)(jb + ro) * DIM_ + col]);
                }
            }
        }
    }
#undef STG_A1
#undef STG_B1
#undef DS_A1
#undef DS_B1
#undef MM1
#undef MFMA16_1
#undef MFMA32_1
}

// ---------------- reduce_a: combine alpha partials -> gqwk[bh][64] ----------------
__global__ __launch_bounds__(256)
void reduce_a(const float* __restrict__ pv1, const float* __restrict__ pms1,
              const float* __restrict__ Wqkv, const float* __restrict__ w_k,
              float* __restrict__ gqwk)
{
    const int b = blockIdx.x / H_, h = blockIdx.x % H_;
    const int t = threadIdx.x;
    __shared__ float Svec[768];
    __shared__ float ew[16];
    __shared__ float Ssh;

    const float* pp = pms1 + (size_t)(b * H_ + h) * 16 * 2;
    float M = pp[0];
    for (int s = 1; s < 16; ++s) M = fmaxf(M, pp[s * 2]);
    if (t < 16) ew[t] = __expf(pp[t * 2] - M);
    __syncthreads();
    if (t == 0) {
        float S = 0.f;
        for (int s = 0; s < 16; ++s) S += ew[s] * pp[s * 2 + 1];
        Ssh = S;
    }
#pragma unroll
    for (int j = 0; j < 3; ++j) {
        const int col = t + j * 256;
        float v = 0.f;
        for (int s = 0; s < 16; ++s)
            v += ew[s] * pv1[((size_t)(b * 16 + s) * 12 + h) * 768 + col];
        Svec[col] = v;
    }
    __syncthreads();
    if (t < 64) {
        const float* wr = Wqkv + (size_t)(h * 64 + t) * 768;
        float gg = 0.f;
        for (int c = 0; c < 768; ++c) gg += wr[c] * Svec[c];
        gqwk[(size_t)(b * H_ + h) * 64 + t] = (gg / Ssh) * w_k[h * 64 + t];
    }
}

// ---------------- beta path: reads gqwk, emits beta partials ----------------
__global__ __launch_bounds__(256)
void fused_b(const unsigned short* __restrict__ kb,
             const float* __restrict__ gqwk,
             float* __restrict__ pv2, float* __restrict__ pms2)
{
    const int bid = blockIdx.x;
    const int bh = bid / NS2, sp = bid % NS2;
    const int b = bh / H_, h = bh % H_;
    const int t = threadIdx.x;
    const int lane8 = t & 7, grp = t >> 3;

    __shared__ float gq_s[64];
    if (t < 64) gq_s[t] = gqwk[(size_t)bh * 64 + t];
    __syncthreads();

    float w8[8];
#pragma unroll
    for (int j = 0; j < 8; j++) w8[j] = gq_s[lane8 * 8 + j];

    const unsigned short* base = kb + ((size_t)(b * N_ + sp * 256) * DIM_)
                                 + h * 64 + lane8 * 8;
    float q[8][8];
    float d[8];
#pragma unroll
    for (int pass = 0; pass < 8; ++pass) {
        const int row = pass * 32 + grp;
        s8v q8 = *(const s8v*)(base + (size_t)row * DIM_);
        float s = 0.f;
#pragma unroll
        for (int j = 0; j < 8; j++) {
            q[pass][j] = bf2f((unsigned short)q8[j]);
            s += q[pass][j] * w8[j];
        }
        s += __shfl_xor(s, 1); s += __shfl_xor(s, 2); s += __shfl_xor(s, 4);
        d[pass] = s * SCALE_;
    }
    float m = d[0];
#pragma unroll
    for (int pass = 1; pass < 8; ++pass) m = fmaxf(m, d[pass]);
    float ssum = 0.f;
    float a8[8] = {};
#pragma unroll
    for (int pass = 0; pass < 8; ++pass) {
        float e = __expf(d[pass] - m);
        ssum += e;
#pragma unroll
        for (int j = 0; j < 8; j++) a8[j] += e * q[pass][j];
    }

    __shared__ float Lm[32], Ls[32];
    __shared__ float La[32][64];
    if (lane8 == 0) { Lm[grp] = m; Ls[grp] = ssum; }
#pragma unroll
    for (int j = 0; j < 8; j++) La[grp][lane8 * 8 + j] = a8[j];
    __syncthreads();

    if (t < 64) {
        float mstar = Lm[0];
#pragma unroll
        for (int g2 = 1; g2 < 32; ++g2) mstar = fmaxf(mstar, Lm[g2]);
        float sstar = 0.f, v = 0.f;
#pragma unroll
        for (int g2 = 0; g2 < 32; ++g2) {
            float e = __expf(Lm[g2] - mstar);
            sstar += Ls[g2] * e;
            v += La[g2][t] * e;
        }
        pv2[(size_t)bid * 64 + t] = v;
        if (t == 0) { pms2[bid * 2] = mstar; pms2[bid * 2 + 1] = sstar; }
    }
}

// combine nsp partials per bh -> gout[bh][64]
__global__ void path_reduce(const float* __restrict__ partv, const float* __restrict__ partms,
                            int nsp, float* __restrict__ gout)
{
    const int bh = blockIdx.x;
    const int t = threadIdx.x;   // 64
    float mstar = partms[(bh * nsp) * 2];
    for (int p = 1; p < nsp; ++p) mstar = fmaxf(mstar, partms[(bh * nsp + p) * 2]);
    float sstar = 0.f, v = 0.f;
    for (int p = 0; p < nsp; ++p) {
        float e = __expf(partms[(bh * nsp + p) * 2] - mstar);
        sstar += partms[(bh * nsp + p) * 2 + 1] * e;
        v += partv[(size_t)(bh * nsp + p) * 64 + t] * e;
    }
    gout[bh * 64 + t] = v / sstar;
}

// ---------------- avec_prep: avec[h][d] = sum_c w_q[h,c] Wq[h*64+c][d] (bf16) -------
__global__ __launch_bounds__(256)
void avec_prep(const float* __restrict__ Wqkv, const float* __restrict__ w_q,
               unsigned short* __restrict__ avecb)
{
    const int h = blockIdx.x;
    const int t = threadIdx.x;
    if (h >= H_) {
#pragma unroll
        for (int j = 0; j < 3; ++j) avecb[(size_t)h * 768 + t + j * 256] = 0;
        return;
    }
    __shared__ float wl[64];
    if (t < 64) wl[t] = w_q[h * 64 + t];
    __syncthreads();
#pragma unroll
    for (int j = 0; j < 3; ++j) {
        const int dcol = t + j * 256;
        float a = 0.f;
        for (int c = 0; c < 64; ++c)
            a += wl[c] * Wqkv[(size_t)(h * 64 + c) * 768 + dcol];
        avecb[(size_t)h * 768 + dcol] = f2bf(a);
    }
}

// ---------------- conversion: x -> xb, Wk -> wqkb, Wv -> wvT ----------
__global__ void cvt_all(const float* __restrict__ x, const float* __restrict__ Wqkv,
                        unsigned short* __restrict__ xb, unsigned short* __restrict__ wqkb,
                        unsigned short* __restrict__ wvT,
                        int n4x, int n4xw)
{
    int i = blockIdx.x * 256 + threadIdx.x;
    if (i < n4xw) {
        const float* src; unsigned short* dst; int k;
        if (i < n4x) { src = x; dst = xb; k = i; }
        else { src = Wqkv + (size_t)DIM_ * DIM_; dst = wqkb; k = i - n4x; }  // Wk rows
        float4 v = ((const float4*)src)[k];
        ushort4 o;
        o.x = f2bf(v.x); o.y = f2bf(v.y); o.z = f2bf(v.z); o.w = f2bf(v.w);
        ((ushort4*)dst)[k] = o;
    } else {
        const int k = i - n4xw;
        const int ii = k % DIM_;
        const int c0 = (k / DIM_) * 4;
        ushort4 o;
        o.x = f2bf(Wqkv[(size_t)(2 * DIM_ + c0 + 0) * DIM_ + ii]);
        o.y = f2bf(Wqkv[(size_t)(2 * DIM_ + c0 + 1) * DIM_ + ii]);
        o.z = f2bf(Wqkv[(size_t)(2 * DIM_ + c0 + 2) * DIM_ + ii]);
        o.w = f2bf(Wqkv[(size_t)(2 * DIM_ + c0 + 3) * DIM_ + ii]);
        *(ushort4*)&wvT[(size_t)ii * DIM_ + c0] = o;
    }
}

// ---------------- fold gk into Wp: W2[b][j][c] = bf16(Wp[j][c] * gk[b*768+c]) --------
__global__ __launch_bounds__(256)
void fold_wp(const float* __restrict__ Wp, const float* __restrict__ gk,
             unsigned short* __restrict__ W2)
{
    int idx = blockIdx.x * 256 + threadIdx.x;
    int e4 = idx * 4;
    int b = (int)((unsigned)e4 / (unsigned)(DIM_ * DIM_));
    int rem = e4 - b * (DIM_ * DIM_);
    int c = rem % DIM_;
    float4 wv = *(const float4*)&Wp[rem];
    const float* gp = &gk[b * DIM_ + c];
    ushort4 o;
    o.x = f2bf(wv.x * gp[0]); o.y = f2bf(wv.y * gp[1]);
    o.z = f2bf(wv.z * gp[2]); o.w = f2bf(wv.w * gp[3]);
    *(ushort4*)&W2[e4] = o;
}

extern "C" void kernel_launch(void* const* d_in, const int* in_sizes, int n_in,
                              void* d_out, int out_size, void* d_ws, size_t ws_size,
                              hipStream_t stream)
{
    const float* x    = (const float*)d_in[0];
    const float* Wqkv = (const float*)d_in[1];
    const float* Wp   = (const float*)d_in[2];
    const float* bp   = (const float*)d_in[3];
    const float* w_q  = (const float*)d_in[4];
    const float* w_k  = (const float*)d_in[5];
    float* out = (float*)d_out;

    constexpr size_t NXB = (size_t)M_ * DIM_;
    constexpr size_t NWK = (size_t)DIM_ * DIM_;
    constexpr size_t NWV = (size_t)DIM_ * DIM_;
    constexpr size_t NKB = (size_t)M_ * DIM_;
    constexpr size_t NW2 = (size_t)B_ * DIM_ * DIM_;

    char* p = (char*)d_ws;
    unsigned short* xb    = (unsigned short*)p; p += NXB * 2;
    unsigned short* wqkb  = (unsigned short*)p; p += NWK * 2;
    unsigned short* wvT   = (unsigned short*)p; p += NWV * 2;
    unsigned short* kb    = (unsigned short*)p; p += NKB * 2;
    unsigned short* w2b   = (unsigned short*)p; p += NW2 * 2;
    unsigned short* w4b   = (unsigned short*)p; p += NW2 * 2;
    unsigned short* avecb = (unsigned short*)p; p += (size_t)16 * 768 * 2;
    float* pv1  = (float*)p; p += (size_t)B_ * 16 * 12 * 768 * 4;
    float* pms1 = (float*)p; p += (size_t)B_ * H_ * 16 * 2 * 4;
    float* pv2  = (float*)p; p += (size_t)B_ * H_ * NS2 * 64 * 4;
    float* pms2 = (float*)p; p += (size_t)B_ * H_ * NS2 * 2 * 4;
    float* gqwk = (float*)p; p += (size_t)B_ * H_ * 64 * 4;
    float* gkv  = (float*)p; p += (size_t)B_ * H_ * 64 * 4;

    // 1) convert x + Wk + Wv^T (one kernel)
    constexpr int N4X  = (int)(NXB / 4);
    constexpr int N4XW = N4X + (int)(NWK / 4);
    constexpr int NTOT = N4XW + (int)(NWV / 4);
    cvt_all<<<NTOT / 256, 256, 0, stream>>>(x, Wqkv, xb, wqkb, wvT, N4X, N4XW);

    // 2) avec[h] = Wq_h^T w_q_h  (bf16 [16][768], zeros h>=12)
    avec_prep<<<16, 256, 0, stream>>>(Wqkv, w_q, avecb);

    // 3) k GEMM (3 col-tiles) + alpha score/wsum blocks (1 col) : 512 blocks = 2.0 rounds
    gemm8<<<128 * 4, 512, 0, stream>>>(xb, DIM_, wqkb, kb, avecb, pv1, pms1, 4);

    // 4) alpha reduce -> gqwk = (Wq_h @ Svec / S) * w_k
    reduce_a<<<B_ * H_, 256, 0, stream>>>(pv1, pms1, Wqkv, w_k, gqwk);

    // 5) beta path partials + reduce
    fused_b<<<B_ * H_ * NS2, 256, 0, stream>>>(kb, gqwk, pv2, pms2);
    path_reduce<<<B_ * H_, 64, 0, stream>>>(pv2, pms2, NS2, gkv);

    // 6) W2[b] = Wp * gk_b (bf16)
    fold_wp<<<(int)(NW2 / 4 / 256), 256, 0, stream>>>(Wp, gkv, w2b);

    // 7) W4 = W2 @ Wv + Wq  (flat [6144,768] GEMM, 144 blocks)
    gemm128<1><<<48 * 3, 512, 0, stream>>>(w2b, DIM_, wvT, nullptr, w4b, nullptr, Wqkv,
                                           DIM_, 3);

    // 8) out = x @ W4_b^T + bp   (768 blocks)
    gemm128<0><<<256 * 3, 512, 0, stream>>>(xb, DIM_, w4b, out, nullptr, bp, nullptr,
                                            DIM_, 3);
}

// Round 15
// 209.536 us; speedup vs baseline: 1.0244x; 1.0244x over previous
//
#include <hip/hip_runtime.h>
#include <hip/hip_bf16.h>
#include <cstdint>
#include <cstddef>

#define B_ 8
#define N_ 4096
#define DIM_ 768
#define H_ 12
#define M_ (B_*N_)        // 32768
#define SCALE_ 0.125f
#define NS2 16
#define KDIM 768
#define NKT 12
#define NITER 6

typedef __attribute__((ext_vector_type(8))) short s8v;
typedef __attribute__((ext_vector_type(4))) float f4v;

__device__ inline float bf2f(unsigned short u) {
    unsigned v = ((unsigned)u) << 16;
    return __builtin_bit_cast(float, v);
}
__device__ inline unsigned short f2bf(float f) {
    unsigned u = __builtin_bit_cast(unsigned, f);
    return (unsigned short)((u + 0x7FFFu + ((u >> 16) & 1u)) >> 16);
}
__device__ inline void gload16(const void* g, void* l) {
    __builtin_amdgcn_global_load_lds(
        (const __attribute__((address_space(1))) void*)g,
        (__attribute__((address_space(3))) void*)l, 16, 0, 0);
}

#define BARX() __builtin_amdgcn_s_barrier()
#define PRIO1() __builtin_amdgcn_s_setprio(1)
#define PRIO0() __builtin_amdgcn_s_setprio(0)
#define VM4() asm volatile("s_waitcnt vmcnt(4)" ::: "memory")
#define VM0() asm volatile("s_waitcnt vmcnt(0)" ::: "memory")

// ---------------- 256x256 8-phase bf16 GEMM + fused alpha score/wsum column ----------
// tn<3 : k GEMM (B = Wk rows tn*256..), store bf16 to kb[row*768 + tn*256 + c].
// tn==3: score block: scores = x@avec^T (MFMA), block softmax, P = E^T X (MFMA),
//        emits pv1[(b*16+slice)*12+h][768] and pms1[bh][slice]{m,s}.
__global__ __launch_bounds__(512, 2)
void gemm8(const unsigned short* __restrict__ A, int ldaE,
           const unsigned short* __restrict__ Bmat,
           unsigned short* __restrict__ Cb,
           const unsigned short* __restrict__ avecb,
           float* __restrict__ pv1, float* __restrict__ pms1,
           int ntn)
{
    __shared__ __align__(16) char smem[131072];   // 2 bufs x 4 regions x 16KB
    const int tid = threadIdx.x;
    const int l = tid & 63, w = tid >> 6;
    const int lr = l & 15, g = l >> 4;
    const int wm = w >> 2, wn = w & 3;

    const int nwg = gridDim.x, cpx = nwg >> 3;
    const int bid = blockIdx.x;
    const int lg = (bid & 7) * cpx + (bid >> 3);
    const int tm = lg / ntn, tn = lg % ntn;
    const int m0 = tm * 256, n0 = tn * 256;

    const long ldaB = (long)ldaE * 2;
    const long ldbB = (long)KDIM * 2;

    const int srA = w * 8 + (l >> 3);
    const int kbs = (l & 7) * 16;
    const int kbx = kbs ^ ((srA & 7) << 4);
    long offA[2], offB[2];
    offA[0] = (long)(srA) * ldaB + kbx;
    offA[1] = (long)(128 + srA) * ldaB + kbx;
    offB[0] = (long)(((srA >> 5)) * 64 + (srA & 31)) * ldbB + kbx;
    offB[1] = (long)((2 + (srA >> 5)) * 64 + (srA & 31)) * ldbB + kbx;

    const char* Abase = (const char*)(A + (size_t)m0 * ldaE);
    const char* Bbase = (const char*)(Bmat + (size_t)n0 * KDIM);

    const int aoff = (wm * 64 + lr) * 128;
    const int boff = (wn * 32 + lr) * 128;
    const int kx0 = (g * 16) ^ ((lr & 7) << 4);
    const int kx1 = (64 + g * 16) ^ ((lr & 7) << 4);

#define STG_A(buf_, qm_, kt_) { \
    const char* s0_ = Abase + (long)(kt_) * 2 + (long)(qm_) * 64 * ldaB; \
    char* d0_ = smem + ((buf_) * 4 + (qm_)) * 16384 + w * 1024; \
    gload16(s0_ + offA[0], d0_); \
    gload16(s0_ + offA[1], d0_ + 8192); }

#define STG_B(buf_, qn_, kt_) { \
    const char* s0_ = Bbase + (long)(kt_) * 2 + (long)(qn_) * 32 * ldbB; \
    char* d0_ = smem + ((buf_) * 4 + 2 + (qn_)) * 16384 + w * 1024; \
    gload16(s0_ + offB[0], d0_); \
    gload16(s0_ + offB[1], d0_ + 8192); }

    if (tn < 3) {
        // ======================= k GEMM (proven path) =======================
        f4v acc[8][4] = {};
        s8v af[4][2];
        s8v bfr[2][2][2];

#define DS_A(buf_, qm_) { \
    const char* ba_ = smem + ((buf_) * 4 + (qm_)) * 16384 + aoff; \
    af[0][0] = *(const s8v*)(ba_ +    0 + kx0); af[0][1] = *(const s8v*)(ba_ +    0 + kx1); \
    af[1][0] = *(const s8v*)(ba_ + 2048 + kx0); af[1][1] = *(const s8v*)(ba_ + 2048 + kx1); \
    af[2][0] = *(const s8v*)(ba_ + 4096 + kx0); af[2][1] = *(const s8v*)(ba_ + 4096 + kx1); \
    af[3][0] = *(const s8v*)(ba_ + 6144 + kx0); af[3][1] = *(const s8v*)(ba_ + 6144 + kx1); }

#define DS_B(buf_, qn_) { \
    const char* bb_ = smem + ((buf_) * 4 + 2 + (qn_)) * 16384 + boff; \
    bfr[qn_][0][0] = *(const s8v*)(bb_ +    0 + kx0); bfr[qn_][0][1] = *(const s8v*)(bb_ +    0 + kx1); \
    bfr[qn_][1][0] = *(const s8v*)(bb_ + 2048 + kx0); bfr[qn_][1][1] = *(const s8v*)(bb_ + 2048 + kx1); }

#define MM(fmg_, fng_, qn_, kk_) \
    acc[fmg_][fng_] = __builtin_amdgcn_mfma_f32_16x16x32_bf16(af[(fmg_)&3][kk_], bfr[qn_][(fng_)&1][kk_], acc[fmg_][fng_], 0, 0, 0);

#define MFMA8(qm_, qn_, kk_) \
    MM((qm_)*4+0, (qn_)*2+0, qn_, kk_) MM((qm_)*4+0, (qn_)*2+1, qn_, kk_) \
    MM((qm_)*4+1, (qn_)*2+0, qn_, kk_) MM((qm_)*4+1, (qn_)*2+1, qn_, kk_) \
    MM((qm_)*4+2, (qn_)*2+0, qn_, kk_) MM((qm_)*4+2, (qn_)*2+1, qn_, kk_) \
    MM((qm_)*4+3, (qn_)*2+0, qn_, kk_) MM((qm_)*4+3, (qn_)*2+1, qn_, kk_)

#define MFMA16(qm_, qn_) { MFMA8(qm_, qn_, 0) MFMA8(qm_, qn_, 1) }

        STG_A(0, 0, 0); STG_B(0, 0, 0); STG_A(0, 1, 0); STG_B(0, 1, 0);
        STG_A(1, 0, 64); STG_B(1, 0, 64);
        VM4(); BARX();

        for (int i = 0; i < NITER; ++i) {
            const int t1k = (2 * i + 1) * 64, t2k = (2 * i + 2) * 64, t3k = (2 * i + 3) * 64;
            const bool h2 = (2 * i + 2) < NKT, h3 = (2 * i + 3) < NKT;
            const bool last = (i == NITER - 1);
            DS_A(0, 0); DS_B(0, 0); STG_B(1, 1, t1k);
            BARX(); PRIO1(); MFMA16(0, 0); PRIO0(); BARX();
            DS_B(0, 1); STG_A(1, 1, t1k);
            BARX(); PRIO1(); MFMA16(0, 1); PRIO0(); BARX();
            DS_A(0, 1); if (h2) STG_A(0, 0, t2k);
            BARX(); PRIO1(); MFMA16(1, 0); PRIO0(); BARX();
            if (h2) STG_B(0, 0, t2k);
            BARX(); PRIO1(); MFMA16(1, 1); PRIO0();
            if (last) { VM0(); } else { VM4(); }
            BARX();
            DS_A(1, 0); DS_B(1, 0); if (h2) STG_A(0, 1, t2k);
            BARX(); PRIO1(); MFMA16(0, 0); PRIO0(); BARX();
            DS_B(1, 1); if (h2) STG_B(0, 1, t2k);
            BARX(); PRIO1(); MFMA16(0, 1); PRIO0(); BARX();
            DS_A(1, 1); if (h3) STG_A(1, 0, t3k);
            BARX(); PRIO1(); MFMA16(1, 0); PRIO0(); BARX();
            if (h3) STG_B(1, 0, t3k);
            BARX(); PRIO1(); MFMA16(1, 1); PRIO0();
            if (last) { VM0(); } else { VM4(); }
            BARX();
        }

        const int c0 = tn * 256;
#pragma unroll
        for (int fmg = 0; fmg < 8; ++fmg) {
#pragma unroll
            for (int fng = 0; fng < 4; ++fng) {
                const int col = c0 + wn * 64 + fng * 16 + lr;
#pragma unroll
                for (int r = 0; r < 4; ++r) {
                    const int row = m0 + wm * 128 + fmg * 16 + g * 4 + r;
                    Cb[(size_t)row * DIM_ + col] = f2bf(acc[fmg][fng][r]);
                }
            }
        }
#undef DS_A
#undef DS_B
#undef MM
#undef MFMA8
#undef MFMA16
    } else {
        // ======================= score block =======================
        const int b = m0 >> 12;
        const int slice = (m0 & (N_ - 1)) >> 8;      // 0..15
        if (w < 2) {
            const int rw = l >> 3;
            const int by = ((l & 7) * 16) ^ (rw << 4);
#pragma unroll
            for (int k6 = 0; k6 < 6; ++k6) {
                const int kt = w * 6 + k6;
                gload16((const char*)avecb + (size_t)rw * 1536 + kt * 128 + by,
                        smem + 32768 + kt * 2048);
                gload16((const char*)avecb + (size_t)(8 + rw) * 1536 + kt * 128 + by,
                        smem + 32768 + kt * 2048 + 1024);
            }
        }
        STG_A(0, 0, 0); STG_A(0, 1, 0);
        STG_A(1, 0, 64); STG_A(1, 1, 64);
        VM4(); BARX();

        // phase 1: scores = x @ avec^T
        f4v sacc[2] = {};
        for (int kt = 0; kt < 12; ++kt) {
            const int buf = kt & 1;
#pragma unroll
            for (int j = 0; j < 2; ++j) {
                const int r0 = w * 32 + j * 16;
                const int qm = (r0 >> 6) & 1, hi = r0 >> 7, loc = r0 & 63;
                const char* ab = smem + (buf * 4 + qm) * 16384 + hi * 8192 + (loc + lr) * 128;
                s8v a0 = *(const s8v*)(ab + kx0);
                s8v a1 = *(const s8v*)(ab + kx1);
                const char* vb = smem + 32768 + kt * 2048 + lr * 128;
                s8v b0 = *(const s8v*)(vb + kx0);
                s8v b1 = *(const s8v*)(vb + kx1);
                sacc[j] = __builtin_amdgcn_mfma_f32_16x16x32_bf16(a0, b0, sacc[j], 0, 0, 0);
                sacc[j] = __builtin_amdgcn_mfma_f32_16x16x32_bf16(a1, b1, sacc[j], 0, 0, 0);
            }
            BARX();
            if (kt + 2 < 12) {
                const int kk2 = (kt + 2) * 64;
                STG_A(buf, 0, kk2); STG_A(buf, 1, kk2);
            }
            if (kt <= 9) { VM4(); } else { VM0(); }
            BARX();
        }

        float dd[8];
#pragma unroll
        for (int j = 0; j < 2; ++j)
#pragma unroll
            for (int r = 0; r < 4; ++r) dd[j * 4 + r] = sacc[j][r] * SCALE_;

        float mw = dd[0];
#pragma unroll
        for (int q2 = 1; q2 < 8; ++q2) mw = fmaxf(mw, dd[q2]);
        mw = fmaxf(mw, __shfl_xor(mw, 16));
        mw = fmaxf(mw, __shfl_xor(mw, 32));
        float* Lm = (float*)(smem + 107008);
        float* Ls = (float*)(smem + 107520);
        if (l < 16) Lm[w * 16 + lr] = mw;
        __syncthreads();
        float mfin = Lm[lr];
#pragma unroll
        for (int w2 = 1; w2 < 8; ++w2) mfin = fmaxf(mfin, Lm[w2 * 16 + lr]);

        float ss = 0.f;
#pragma unroll
        for (int j = 0; j < 2; ++j)
#pragma unroll
            for (int r = 0; r < 4; ++r) {
                const float e = __expf(dd[j * 4 + r] - mfin);
                ss += e;
                const int row = w * 32 + j * 16 + g * 4 + r;
                *(unsigned short*)(smem + 98304 + lr * 544 + row * 2) = f2bf(e);
            }
        ss += __shfl_xor(ss, 16);
        ss += __shfl_xor(ss, 32);
        if (l < 16) Ls[w * 16 + lr] = ss;
        __syncthreads();

        if (tid < 12) {
            float S = 0.f;
#pragma unroll
            for (int w2 = 0; w2 < 8; ++w2) S += Ls[w2 * 16 + tid];
            float M2 = Lm[tid];
#pragma unroll
            for (int w2 = 1; w2 < 8; ++w2) M2 = fmaxf(M2, Lm[w2 * 16 + tid]);
            pms1[((size_t)(b * H_ + tid) * 16 + slice) * 2 + 0] = M2;
            pms1[((size_t)(b * H_ + tid) * 16 + slice) * 2 + 1] = S;
        }
        __syncthreads();

        // phase 2: P[h][d] = sum_n E[n][h] x[n][d]
        for (int it = 0; it < 6; ++it) {
            const int ktA = it * 2, ktB = it * 2 + 1;
            STG_A(0, 0, ktA * 64); STG_A(0, 1, ktA * 64);
            STG_A(1, 0, ktB * 64); STG_A(1, 1, ktB * 64);
            VM0(); BARX();
            const int buf = w >> 2;
            const int kt = it * 2 + buf;
            const int d0 = (w & 3) * 16;
            const int dby = (d0 + (l & 15)) * 2;
            f4v pacc = {};
#pragma unroll
            for (int c = 0; c < 8; ++c) {
                s8v ae = *(const s8v*)(smem + 98304 + (l & 15) * 544
                                       + (c * 32 + (l >> 4) * 8) * 2);
                const char* xr = smem + (buf * 4 + ((c >> 1) & 1)) * 16384 + (c >> 2) * 8192;
                const int nb = (c & 1) * 32 + (l >> 4) * 8;
                s8v bx;
#pragma unroll
                for (int j = 0; j < 8; ++j)
                    bx[j] = (short)*(const unsigned short*)(xr + (nb + j) * 128 + (dby ^ (j << 4)));
                pacc = __builtin_amdgcn_mfma_f32_16x16x32_bf16(ae, bx, pacc, 0, 0, 0);
            }
            if ((l >> 4) < 3) {
#pragma unroll
                for (int r = 0; r < 4; ++r) {
                    const int h = (l >> 4) * 4 + r;
                    pv1[((size_t)(b * 16 + slice) * 12 + h) * 768
                        + kt * 64 + d0 + (l & 15)] = pacc[r];
                }
            }
            BARX();
        }
    }
#undef STG_A
#undef STG_B
}

// ---------------- 128x256 4-phase bf16 GEMM (unchanged, proven) ----------------
template<int MODE>
__global__ __launch_bounds__(512, 2)
void gemm128(const unsigned short* __restrict__ A, int ldaE,
             const unsigned short* __restrict__ Bmat,
             float* __restrict__ Cf, unsigned short* __restrict__ CbO,
             const float* __restrict__ bias, const float* __restrict__ addW,
             int Nc, int ntn)
{
    __shared__ __align__(16) char smem[98304];
    const int tid = threadIdx.x;
    const int l = tid & 63, w = tid >> 6;
    const int lr = l & 15, g = l >> 4;
    const int wm = w >> 2, wn = w & 3;

    const int nwg = gridDim.x, cpx = nwg >> 3;
    const int bid = blockIdx.x;
    const int lg = (bid & 7) * cpx + (bid >> 3);
    const int tm = lg / ntn, tn = lg % ntn;
    const int m0 = tm * 128, n0 = tn * 256;

    const long ldaB = (long)ldaE * 2;
    const long ldbB = (long)KDIM * 2;

    const unsigned short* Bp = Bmat;
    if (MODE == 0) Bp = Bmat + (size_t)(m0 >> 12) * (DIM_ * DIM_);

    const int srA = w * 8 + (l >> 3);
    const int kbs = (l & 7) * 16;
    const int kbx = kbs ^ ((srA & 7) << 4);
    long offA[2], offB[2];
    offA[0] = (long)(srA) * ldaB + kbx;
    offA[1] = (long)(64 + srA) * ldaB + kbx;
    offB[0] = (long)(((srA >> 5)) * 64 + (srA & 31)) * ldbB + kbx;
    offB[1] = (long)((2 + (srA >> 5)) * 64 + (srA & 31)) * ldbB + kbx;

    const char* Abase = (const char*)(A + (size_t)m0 * ldaE);
    const char* Bbase = (const char*)(Bp + (size_t)n0 * KDIM);

    const int aoff = (wm * 64 + lr) * 128;
    const int boff = (wn * 32 + lr) * 128;
    const int kx0 = (g * 16) ^ ((lr & 7) << 4);
    const int kx1 = (64 + g * 16) ^ ((lr & 7) << 4);

    f4v acc[4][4] = {};
    s8v af[4][2];
    s8v bfr[2][2][2];

#define STG_A1(buf_, kt_) { \
    const char* s0_ = Abase + (long)(kt_) * 2; \
    char* d0_ = smem + ((buf_) * 3) * 16384 + w * 1024; \
    gload16(s0_ + offA[0], d0_); \
    gload16(s0_ + offA[1], d0_ + 8192); }

#define STG_B1(buf_, qn_, kt_) { \
    const char* s0_ = Bbase + (long)(kt_) * 2 + (long)(qn_) * 32 * ldbB; \
    char* d0_ = smem + ((buf_) * 3 + 1 + (qn_)) * 16384 + w * 1024; \
    gload16(s0_ + offB[0], d0_); \
    gload16(s0_ + offB[1], d0_ + 8192); }

#define DS_A1(buf_) { \
    const char* ba_ = smem + ((buf_) * 3) * 16384 + aoff; \
    af[0][0] = *(const s8v*)(ba_ +    0 + kx0); af[0][1] = *(const s8v*)(ba_ +    0 + kx1); \
    af[1][0] = *(const s8v*)(ba_ + 2048 + kx0); af[1][1] = *(const s8v*)(ba_ + 2048 + kx1); \
    af[2][0] = *(const s8v*)(ba_ + 4096 + kx0); af[2][1] = *(const s8v*)(ba_ + 4096 + kx1); \
    af[3][0] = *(const s8v*)(ba_ + 6144 + kx0); af[3][1] = *(const s8v*)(ba_ + 6144 + kx1); }

#define DS_B1(buf_, qn_) { \
    const char* bb_ = smem + ((buf_) * 3 + 1 + (qn_)) * 16384 + boff; \
    bfr[qn_][0][0] = *(const s8v*)(bb_ +    0 + kx0); bfr[qn_][0][1] = *(const s8v*)(bb_ +    0 + kx1); \
    bfr[qn_][1][0] = *(const s8v*)(bb_ + 2048 + kx0); bfr[qn_][1][1] = *(const s8v*)(bb_ + 2048 + kx1); }

#define MM1(fm_, fng_, qn_, kk_) \
    acc[fm_][fng_] = __builtin_amdgcn_mfma_f32_16x16x32_bf16(af[fm_][kk_], bfr[qn_][(fng_)&1][kk_], acc[fm_][fng_], 0, 0, 0);

#define MFMA16_1(qn_, kk_) \
    MM1(0, (qn_)*2+0, qn_, kk_) MM1(0, (qn_)*2+1, qn_, kk_) \
    MM1(1, (qn_)*2+0, qn_, kk_) MM1(1, (qn_)*2+1, qn_, kk_) \
    MM1(2, (qn_)*2+0, qn_, kk_) MM1(2, (qn_)*2+1, qn_, kk_) \
    MM1(3, (qn_)*2+0, qn_, kk_) MM1(3, (qn_)*2+1, qn_, kk_)

#define MFMA32_1(qn_) { MFMA16_1(qn_, 0) MFMA16_1(qn_, 1) }

    STG_A1(0, 0); STG_B1(0, 0, 0); STG_B1(0, 1, 0);
    STG_A1(1, 64); STG_B1(1, 0, 64);
    VM4(); BARX();

    for (int i = 0; i < NITER; ++i) {
        const int t1k = (2 * i + 1) * 64, t2k = (2 * i + 2) * 64, t3k = (2 * i + 3) * 64;
        const bool h2 = (2 * i + 2) < NKT, h3 = (2 * i + 3) < NKT;
        const bool last = (i == NITER - 1);
        DS_A1(0); DS_B1(0, 0); STG_B1(1, 1, t1k);
        BARX(); PRIO1(); MFMA32_1(0); PRIO0(); BARX();
        DS_B1(0, 1); if (h2) { STG_A1(0, t2k); STG_B1(0, 0, t2k); }
        BARX(); PRIO1(); MFMA32_1(1); PRIO0();
        if (last) { VM0(); } else { VM4(); }
        BARX();
        DS_A1(1); DS_B1(1, 0); if (h2) STG_B1(0, 1, t2k);
        BARX(); PRIO1(); MFMA32_1(0); PRIO0(); BARX();
        DS_B1(1, 1); if (h3) { STG_A1(1, t3k); STG_B1(1, 0, t3k); }
        BARX(); PRIO1(); MFMA32_1(1); PRIO0();
        if (last) { VM0(); } else { VM4(); }
        BARX();
    }

    const int jb = m0 % DIM_;   // row offset within batch (MODE 1)
#pragma unroll
    for (int fm = 0; fm < 4; ++fm) {
#pragma unroll
        for (int fng = 0; fng < 4; ++fng) {
            const int col = n0 + wn * 64 + fng * 16 + lr;
#pragma unroll
            for (int r = 0; r < 4; ++r) {
                const int ro = wm * 64 + fm * 16 + g * 4 + r;
                const int row = m0 + ro;
                if (MODE == 0) {
                    Cf[(size_t)row * Nc + col] = acc[fm][fng][r] + bias[col];
                } else {
                    CbO[(size_t)row * Nc + col] =
                        f2bf(acc[fm][fng][r] + addW[(size_t)(jb + ro) * DIM_ + col]);
                }
            }
        }
    }
#undef STG_A1
#undef STG_B1
#undef DS_A1
#undef DS_B1
#undef MM1
#undef MFMA16_1
#undef MFMA32_1
}

// ---------------- reduce_a: combine alpha partials -> gqwk[bh][64] (coalesced) -------
__global__ __launch_bounds__(256)
void reduce_a(const float* __restrict__ pv1, const float* __restrict__ pms1,
              const float* __restrict__ Wqkv, const float* __restrict__ w_k,
              float* __restrict__ gqwk)
{
    const int b = blockIdx.x / H_, h = blockIdx.x % H_;
    const int t = threadIdx.x;
    const int w = t >> 6, l = t & 63;
    __shared__ float Svec[768];
    __shared__ float ew[16];
    __shared__ float Ssh;

    const float* pp = pms1 + (size_t)(b * H_ + h) * 16 * 2;
    float M = pp[0];
    for (int s = 1; s < 16; ++s) M = fmaxf(M, pp[s * 2]);
    if (t < 16) ew[t] = __expf(pp[t * 2] - M);
    __syncthreads();
    if (t == 0) {
        float S = 0.f;
        for (int s = 0; s < 16; ++s) S += ew[s] * pp[s * 2 + 1];
        Ssh = S;
    }
#pragma unroll
    for (int j = 0; j < 3; ++j) {
        const int col = t + j * 256;
        float v = 0.f;
        for (int s = 0; s < 16; ++s)
            v += ew[s] * pv1[((size_t)(b * 16 + s) * 12 + h) * 768 + col];
        Svec[col] = v;
    }
    __syncthreads();

    // matvec: wave w owns outputs w*16..w*16+15; 64 lanes split 768 cols (coalesced)
    const float invS = 1.f / Ssh;
    for (int i = 0; i < 16; ++i) {
        const int o = w * 16 + i;
        const float* wr = Wqkv + (size_t)(h * 64 + o) * 768;
        float s = 0.f;
#pragma unroll
        for (int j = 0; j < 12; ++j)
            s += wr[l + j * 64] * Svec[l + j * 64];
        s += __shfl_xor(s, 1); s += __shfl_xor(s, 2); s += __shfl_xor(s, 4);
        s += __shfl_xor(s, 8); s += __shfl_xor(s, 16); s += __shfl_xor(s, 32);
        if (l == 0)
            gqwk[(size_t)(b * H_ + h) * 64 + o] = (s * invS) * w_k[h * 64 + o];
    }
}

// ---------------- beta path: reads gqwk, emits beta partials ----------------
__global__ __launch_bounds__(256)
void fused_b(const unsigned short* __restrict__ kb,
             const float* __restrict__ gqwk,
             float* __restrict__ pv2, float* __restrict__ pms2)
{
    const int bid = blockIdx.x;
    const int bh = bid / NS2, sp = bid % NS2;
    const int b = bh / H_, h = bh % H_;
    const int t = threadIdx.x;
    const int lane8 = t & 7, grp = t >> 3;

    __shared__ float gq_s[64];
    if (t < 64) gq_s[t] = gqwk[(size_t)bh * 64 + t];
    __syncthreads();

    float w8[8];
#pragma unroll
    for (int j = 0; j < 8; j++) w8[j] = gq_s[lane8 * 8 + j];

    const unsigned short* base = kb + ((size_t)(b * N_ + sp * 256) * DIM_)
                                 + h * 64 + lane8 * 8;
    float q[8][8];
    float d[8];
#pragma unroll
    for (int pass = 0; pass < 8; ++pass) {
        const int row = pass * 32 + grp;
        s8v q8 = *(const s8v*)(base + (size_t)row * DIM_);
        float s = 0.f;
#pragma unroll
        for (int j = 0; j < 8; j++) {
            q[pass][j] = bf2f((unsigned short)q8[j]);
            s += q[pass][j] * w8[j];
        }
        s += __shfl_xor(s, 1); s += __shfl_xor(s, 2); s += __shfl_xor(s, 4);
        d[pass] = s * SCALE_;
    }
    float m = d[0];
#pragma unroll
    for (int pass = 1; pass < 8; ++pass) m = fmaxf(m, d[pass]);
    float ssum = 0.f;
    float a8[8] = {};
#pragma unroll
    for (int pass = 0; pass < 8; ++pass) {
        float e = __expf(d[pass] - m);
        ssum += e;
#pragma unroll
        for (int j = 0; j < 8; j++) a8[j] += e * q[pass][j];
    }

    __shared__ float Lm[32], Ls[32];
    __shared__ float La[32][64];
    if (lane8 == 0) { Lm[grp] = m; Ls[grp] = ssum; }
#pragma unroll
    for (int j = 0; j < 8; j++) La[grp][lane8 * 8 + j] = a8[j];
    __syncthreads();

    if (t < 64) {
        float mstar = Lm[0];
#pragma unroll
        for (int g2 = 1; g2 < 32; ++g2) mstar = fmaxf(mstar, Lm[g2]);
        float sstar = 0.f, v = 0.f;
#pragma unroll
        for (int g2 = 0; g2 < 32; ++g2) {
            float e = __expf(Lm[g2] - mstar);
            sstar += Ls[g2] * e;
            v += La[g2][t] * e;
        }
        pv2[(size_t)bid * 64 + t] = v;
        if (t == 0) { pms2[bid * 2] = mstar; pms2[bid * 2 + 1] = sstar; }
    }
}

// combine nsp partials per bh -> gout[bh][64]
__global__ void path_reduce(const float* __restrict__ partv, const float* __restrict__ partms,
                            int nsp, float* __restrict__ gout)
{
    const int bh = blockIdx.x;
    const int t = threadIdx.x;   // 64
    float mstar = partms[(bh * nsp) * 2];
    for (int p = 1; p < nsp; ++p) mstar = fmaxf(mstar, partms[(bh * nsp + p) * 2]);
    float sstar = 0.f, v = 0.f;
    for (int p = 0; p < nsp; ++p) {
        float e = __expf(partms[(bh * nsp + p) * 2] - mstar);
        sstar += partms[(bh * nsp + p) * 2 + 1] * e;
        v += partv[(size_t)(bh * nsp + p) * 64 + t] * e;
    }
    gout[bh * 64 + t] = v / sstar;
}

// ---------------- avec_prep: avec[h][d] = sum_c w_q[h,c] Wq[h*64+c][d] (bf16) -------
__global__ __launch_bounds__(256)
void avec_prep(const float* __restrict__ Wqkv, const float* __restrict__ w_q,
               unsigned short* __restrict__ avecb)
{
    const int h = blockIdx.x;
    const int t = threadIdx.x;
    if (h >= H_) {
#pragma unroll
        for (int j = 0; j < 3; ++j) avecb[(size_t)h * 768 + t + j * 256] = 0;
        return;
    }
    __shared__ float wl[64];
    if (t < 64) wl[t] = w_q[h * 64 + t];
    __syncthreads();
#pragma unroll
    for (int j = 0; j < 3; ++j) {
        const int dcol = t + j * 256;
        float a = 0.f;
        for (int c = 0; c < 64; ++c)
            a += wl[c] * Wqkv[(size_t)(h * 64 + c) * 768 + dcol];
        avecb[(size_t)h * 768 + dcol] = f2bf(a);
    }
}

// ---------------- conversion: x -> xb, Wk -> wqkb, Wv -> wvT ----------
__global__ void cvt_all(const float* __restrict__ x, const float* __restrict__ Wqkv,
                        unsigned short* __restrict__ xb, unsigned short* __restrict__ wqkb,
                        unsigned short* __restrict__ wvT,
                        int n4x, int n4xw)
{
    int i = blockIdx.x * 256 + threadIdx.x;
    if (i < n4xw) {
        const float* src; unsigned short* dst; int k;
        if (i < n4x) { src = x; dst = xb; k = i; }
        else { src = Wqkv + (size_t)DIM_ * DIM_; dst = wqkb; k = i - n4x; }  // Wk rows
        float4 v = ((const float4*)src)[k];
        ushort4 o;
        o.x = f2bf(v.x); o.y = f2bf(v.y); o.z = f2bf(v.z); o.w = f2bf(v.w);
        ((ushort4*)dst)[k] = o;
    } else {
        const int k = i - n4xw;
        const int ii = k % DIM_;
        const int c0 = (k / DIM_) * 4;
        ushort4 o;
        o.x = f2bf(Wqkv[(size_t)(2 * DIM_ + c0 + 0) * DIM_ + ii]);
        o.y = f2bf(Wqkv[(size_t)(2 * DIM_ + c0 + 1) * DIM_ + ii]);
        o.z = f2bf(Wqkv[(size_t)(2 * DIM_ + c0 + 2) * DIM_ + ii]);
        o.w = f2bf(Wqkv[(size_t)(2 * DIM_ + c0 + 3) * DIM_ + ii]);
        *(ushort4*)&wvT[(size_t)ii * DIM_ + c0] = o;
    }
}

// ---------------- fold gk into Wp: W2[b][j][c] = bf16(Wp[j][c] * gk[b*768+c]) --------
__global__ __launch_bounds__(256)
void fold_wp(const float* __restrict__ Wp, const float* __restrict__ gk,
             unsigned short* __restrict__ W2)
{
    int idx = blockIdx.x * 256 + threadIdx.x;
    int e4 = idx * 4;
    int b = (int)((unsigned)e4 / (unsigned)(DIM_ * DIM_));
    int rem = e4 - b * (DIM_ * DIM_);
    int c = rem % DIM_;
    float4 wv = *(const float4*)&Wp[rem];
    const float* gp = &gk[b * DIM_ + c];
    ushort4 o;
    o.x = f2bf(wv.x * gp[0]); o.y = f2bf(wv.y * gp[1]);
    o.z = f2bf(wv.z * gp[2]); o.w = f2bf(wv.w * gp[3]);
    *(ushort4*)&W2[e4] = o;
}

extern "C" void kernel_launch(void* const* d_in, const int* in_sizes, int n_in,
                              void* d_out, int out_size, void* d_ws, size_t ws_size,
                              hipStream_t stream)
{
    const float* x    = (const float*)d_in[0];
    const float* Wqkv = (const float*)d_in[1];
    const float* Wp   = (const float*)d_in[2];
    const float* bp   = (const float*)d_in[3];
    const float* w_q  = (const float*)d_in[4];
    const float* w_k  = (const float*)d_in[5];
    float* out = (float*)d_out;

    constexpr size_t NXB = (size_t)M_ * DIM_;
    constexpr size_t NWK = (size_t)DIM_ * DIM_;
    constexpr size_t NWV = (size_t)DIM_ * DIM_;
    constexpr size_t NKB = (size_t)M_ * DIM_;
    constexpr size_t NW2 = (size_t)B_ * DIM_ * DIM_;

    char* p = (char*)d_ws;
    unsigned short* xb    = (unsigned short*)p; p += NXB * 2;
    unsigned short* wqkb  = (unsigned short*)p; p += NWK * 2;
    unsigned short* wvT   = (unsigned short*)p; p += NWV * 2;
    unsigned short* kb    = (unsigned short*)p; p += NKB * 2;
    unsigned short* w2b   = (unsigned short*)p; p += NW2 * 2;
    unsigned short* w4b   = (unsigned short*)p; p += NW2 * 2;
    unsigned short* avecb = (unsigned short*)p; p += (size_t)16 * 768 * 2;
    float* pv1  = (float*)p; p += (size_t)B_ * 16 * 12 * 768 * 4;
    float* pms1 = (float*)p; p += (size_t)B_ * H_ * 16 * 2 * 4;
    float* pv2  = (float*)p; p += (size_t)B_ * H_ * NS2 * 64 * 4;
    float* pms2 = (float*)p; p += (size_t)B_ * H_ * NS2 * 2 * 4;
    float* gqwk = (float*)p; p += (size_t)B_ * H_ * 64 * 4;
    float* gkv  = (float*)p; p += (size_t)B_ * H_ * 64 * 4;

    // 1) convert x + Wk + Wv^T (one kernel)
    constexpr int N4X  = (int)(NXB / 4);
    constexpr int N4XW = N4X + (int)(NWK / 4);
    constexpr int NTOT = N4XW + (int)(NWV / 4);
    cvt_all<<<NTOT / 256, 256, 0, stream>>>(x, Wqkv, xb, wqkb, wvT, N4X, N4XW);

    // 2) avec[h] = Wq_h^T w_q_h  (bf16 [16][768], zeros h>=12)
    avec_prep<<<16, 256, 0, stream>>>(Wqkv, w_q, avecb);

    // 3) k GEMM (3 col-tiles) + alpha score/wsum blocks (1 col): 512 blocks = 2.0 rounds
    gemm8<<<128 * 4, 512, 0, stream>>>(xb, DIM_, wqkb, kb, avecb, pv1, pms1, 4);

    // 4) alpha reduce -> gqwk = (Wq_h @ Svec / S) * w_k
    reduce_a<<<B_ * H_, 256, 0, stream>>>(pv1, pms1, Wqkv, w_k, gqwk);

    // 5) beta path partials + reduce
    fused_b<<<B_ * H_ * NS2, 256, 0, stream>>>(kb, gqwk, pv2, pms2);
    path_reduce<<<B_ * H_, 64, 0, stream>>>(pv2, pms2, NS2, gkv);

    // 6) W2[b] = Wp * gk_b (bf16)
    fold_wp<<<(int)(NW2 / 4 / 256), 256, 0, stream>>>(Wp, gkv, w2b);

    // 7) W4 = W2 @ Wv + Wq  (flat [6144,768] GEMM, 144 blocks)
    gemm128<1><<<48 * 3, 512, 0, stream>>>(w2b, DIM_, wvT, nullptr, w4b, nullptr, Wqkv,
                                           DIM_, 3);

    // 8) out = x @ W4_b^T + bp   (768 blocks)
    gemm128<0><<<256 * 3, 512, 0, stream>>>(xb, DIM_, w4b, out, nullptr, bp, nullptr,
                                            DIM_, 3);
}

// Round 16
// 199.944 us; speedup vs baseline: 1.0736x; 1.0480x over previous
//
#include <hip/hip_runtime.h>
#include <hip/hip_bf16.h>
#include <cstdint>
#include <cstddef>

#define B_ 8
#define N_ 4096
#define DIM_ 768
#define H_ 12
#define M_ (B_*N_)        // 32768
#define SCALE_ 0.125f
#define KDIM 768
#define NKT 12
#define NITER 6

typedef __attribute__((ext_vector_type(8))) short s8v;
typedef __attribute__((ext_vector_type(4))) float f4v;

__device__ inline float bf2f(unsigned short u) {
    unsigned v = ((unsigned)u) << 16;
    return __builtin_bit_cast(float, v);
}
__device__ inline unsigned short f2bf(float f) {
    unsigned u = __builtin_bit_cast(unsigned, f);
    return (unsigned short)((u + 0x7FFFu + ((u >> 16) & 1u)) >> 16);
}
__device__ inline void gload16(const void* g, void* l) {
    __builtin_amdgcn_global_load_lds(
        (const __attribute__((address_space(1))) void*)g,
        (__attribute__((address_space(3))) void*)l, 16, 0, 0);
}

#define BARX() __builtin_amdgcn_s_barrier()
#define PRIO1() __builtin_amdgcn_s_setprio(1)
#define PRIO0() __builtin_amdgcn_s_setprio(0)
#define VM4() asm volatile("s_waitcnt vmcnt(4)" ::: "memory")
#define VM0() asm volatile("s_waitcnt vmcnt(0)" ::: "memory")

// ---------------- score_pass: per (b, 256-row slice): scores = x @ V^T (MFMA),
// block softmax, P = E^T X (MFMA, LDS-restaged x).  [R15 score-block, standalone]
// PATH 0: V = avec [16][768] shared.  PATH 1: V = bvecs [B][16][768] per batch.
// Emits pv[(b*16+slice)*12+h][768] and pms[bh][slice]{m,s}.  Grid: 128 blocks.
template<int PATH>
__global__ __launch_bounds__(512, 2)
void score_pass(const unsigned short* __restrict__ xb,
                const unsigned short* __restrict__ Vmat,
                float* __restrict__ pv, float* __restrict__ pms)
{
    __shared__ __align__(16) char smem[110592];
    const int tid = threadIdx.x;
    const int l = tid & 63, w = tid >> 6;
    const int lr = l & 15, g = l >> 4;

    const int nwg = gridDim.x, cpx = nwg >> 3;
    const int bid = blockIdx.x;
    const int tm = (bid & 7) * cpx + (bid >> 3);
    const int m0 = tm * 256;
    const int b = m0 >> 12;
    const int slice = (m0 & (N_ - 1)) >> 8;      // 0..15

    const long ldaB = (long)KDIM * 2;
    const int srA = w * 8 + (l >> 3);
    const int kbs = (l & 7) * 16;
    const int kbx = kbs ^ ((srA & 7) << 4);
    long offA[2];
    offA[0] = (long)(srA) * ldaB + kbx;
    offA[1] = (long)(128 + srA) * ldaB + kbx;

    const char* Abase = (const char*)(xb + (size_t)m0 * KDIM);
    const char* Vbase = (const char*)Vmat + (PATH ? (size_t)b * 16 * KDIM * 2 : 0);

    const int kx0 = (g * 16) ^ ((lr & 7) << 4);
    const int kx1 = (64 + g * 16) ^ ((lr & 7) << 4);

#define STG_A(buf_, qm_, kt_) { \
    const char* s0_ = Abase + (long)(kt_) * 2 + (long)(qm_) * 64 * ldaB; \
    char* d0_ = smem + ((buf_) * 4 + (qm_)) * 16384 + w * 1024; \
    gload16(s0_ + offA[0], d0_); \
    gload16(s0_ + offA[1], d0_ + 8192); }

    // stage V (waves 0,1; pre-swizzled source, linear dst) at smem+32768
    if (w < 2) {
        const int rw = l >> 3;
        const int by = ((l & 7) * 16) ^ (rw << 4);
#pragma unroll
        for (int k6 = 0; k6 < 6; ++k6) {
            const int kt = w * 6 + k6;
            gload16(Vbase + (size_t)rw * 1536 + kt * 128 + by,
                    smem + 32768 + kt * 2048);
            gload16(Vbase + (size_t)(8 + rw) * 1536 + kt * 128 + by,
                    smem + 32768 + kt * 2048 + 1024);
        }
    }
    STG_A(0, 0, 0); STG_A(0, 1, 0);
    STG_A(1, 0, 64); STG_A(1, 1, 64);
    VM4(); BARX();

    // phase 1: scores = x @ V^T
    f4v sacc[2] = {};
    for (int kt = 0; kt < 12; ++kt) {
        const int buf = kt & 1;
#pragma unroll
        for (int j = 0; j < 2; ++j) {
            const int r0 = w * 32 + j * 16;
            const int qm = (r0 >> 6) & 1, hi = r0 >> 7, loc = r0 & 63;
            const char* ab = smem + (buf * 4 + qm) * 16384 + hi * 8192 + (loc + lr) * 128;
            s8v a0 = *(const s8v*)(ab + kx0);
            s8v a1 = *(const s8v*)(ab + kx1);
            const char* vb = smem + 32768 + kt * 2048 + lr * 128;
            s8v b0 = *(const s8v*)(vb + kx0);
            s8v b1 = *(const s8v*)(vb + kx1);
            sacc[j] = __builtin_amdgcn_mfma_f32_16x16x32_bf16(a0, b0, sacc[j], 0, 0, 0);
            sacc[j] = __builtin_amdgcn_mfma_f32_16x16x32_bf16(a1, b1, sacc[j], 0, 0, 0);
        }
        BARX();
        if (kt + 2 < 12) {
            const int kk2 = (kt + 2) * 64;
            STG_A(buf, 0, kk2); STG_A(buf, 1, kk2);
        }
        if (kt <= 9) { VM4(); } else { VM0(); }
        BARX();
    }

    float dd[8];
#pragma unroll
    for (int j = 0; j < 2; ++j)
#pragma unroll
        for (int r = 0; r < 4; ++r) dd[j * 4 + r] = sacc[j][r] * SCALE_;

    float mw = dd[0];
#pragma unroll
    for (int q2 = 1; q2 < 8; ++q2) mw = fmaxf(mw, dd[q2]);
    mw = fmaxf(mw, __shfl_xor(mw, 16));
    mw = fmaxf(mw, __shfl_xor(mw, 32));
    float* Lm = (float*)(smem + 107008);
    float* Ls = (float*)(smem + 107520);
    if (l < 16) Lm[w * 16 + lr] = mw;
    __syncthreads();
    float mfin = Lm[lr];
#pragma unroll
    for (int w2 = 1; w2 < 8; ++w2) mfin = fmaxf(mfin, Lm[w2 * 16 + lr]);

    float ss = 0.f;
#pragma unroll
    for (int j = 0; j < 2; ++j)
#pragma unroll
        for (int r = 0; r < 4; ++r) {
            const float e = __expf(dd[j * 4 + r] - mfin);
            ss += e;
            const int row = w * 32 + j * 16 + g * 4 + r;
            *(unsigned short*)(smem + 98304 + lr * 544 + row * 2) = f2bf(e);
        }
    ss += __shfl_xor(ss, 16);
    ss += __shfl_xor(ss, 32);
    if (l < 16) Ls[w * 16 + lr] = ss;
    __syncthreads();

    if (tid < 12) {
        float S = 0.f;
#pragma unroll
        for (int w2 = 0; w2 < 8; ++w2) S += Ls[w2 * 16 + tid];
        float M2 = Lm[tid];
#pragma unroll
        for (int w2 = 1; w2 < 8; ++w2) M2 = fmaxf(M2, Lm[w2 * 16 + tid]);
        pms[((size_t)(b * H_ + tid) * 16 + slice) * 2 + 0] = M2;
        pms[((size_t)(b * H_ + tid) * 16 + slice) * 2 + 1] = S;
    }
    __syncthreads();

    // phase 2: P[h][d] = sum_n E[n][h] x[n][d]  (restage x, MFMA A=E^T B=X)
    for (int it = 0; it < 6; ++it) {
        const int ktA = it * 2, ktB = it * 2 + 1;
        STG_A(0, 0, ktA * 64); STG_A(0, 1, ktA * 64);
        STG_A(1, 0, ktB * 64); STG_A(1, 1, ktB * 64);
        VM0(); BARX();
        const int buf = w >> 2;
        const int kt = it * 2 + buf;
        const int d0 = (w & 3) * 16;
        const int dby = (d0 + (l & 15)) * 2;
        f4v pacc = {};
#pragma unroll
        for (int c = 0; c < 8; ++c) {
            s8v ae = *(const s8v*)(smem + 98304 + (l & 15) * 544
                                   + (c * 32 + (l >> 4) * 8) * 2);
            const char* xr = smem + (buf * 4 + ((c >> 1) & 1)) * 16384 + (c >> 2) * 8192;
            const int nb = (c & 1) * 32 + (l >> 4) * 8;
            s8v bx;
#pragma unroll
            for (int j = 0; j < 8; ++j)
                bx[j] = (short)*(const unsigned short*)(xr + (nb + j) * 128 + (dby ^ (j << 4)));
            pacc = __builtin_amdgcn_mfma_f32_16x16x32_bf16(ae, bx, pacc, 0, 0, 0);
        }
        if ((l >> 4) < 3) {
#pragma unroll
            for (int r = 0; r < 4; ++r) {
                const int h = (l >> 4) * 4 + r;
                pv[((size_t)(b * 16 + slice) * 12 + h) * 768
                   + kt * 64 + d0 + (l & 15)] = pacc[r];
            }
        }
        BARX();
    }
#undef STG_A
}

// ---------------- 128x256 4-phase bf16 GEMM (unchanged, proven) ----------------
// MODE 0: Cf[row,col] = A@B_b^T + bias[col] (f32); B_b per batch (row/4096).
// MODE 1: CbO[row,col] = bf16(A@B^T + addW[(row%768)*768+col]); B shared (wvT).
template<int MODE>
__global__ __launch_bounds__(512, 2)
void gemm128(const unsigned short* __restrict__ A, int ldaE,
             const unsigned short* __restrict__ Bmat,
             float* __restrict__ Cf, unsigned short* __restrict__ CbO,
             const float* __restrict__ bias, const float* __restrict__ addW,
             int Nc, int ntn)
{
    __shared__ __align__(16) char smem[98304];
    const int tid = threadIdx.x;
    const int l = tid & 63, w = tid >> 6;
    const int lr = l & 15, g = l >> 4;
    const int wm = w >> 2, wn = w & 3;

    const int nwg = gridDim.x, cpx = nwg >> 3;
    const int bid = blockIdx.x;
    const int lg = (bid & 7) * cpx + (bid >> 3);
    const int tm = lg / ntn, tn = lg % ntn;
    const int m0 = tm * 128, n0 = tn * 256;

    const long ldaB = (long)ldaE * 2;
    const long ldbB = (long)KDIM * 2;

    const unsigned short* Bp = Bmat;
    if (MODE == 0) Bp = Bmat + (size_t)(m0 >> 12) * (DIM_ * DIM_);

    const int srA = w * 8 + (l >> 3);
    const int kbs = (l & 7) * 16;
    const int kbx = kbs ^ ((srA & 7) << 4);
    long offA[2], offB[2];
    offA[0] = (long)(srA) * ldaB + kbx;
    offA[1] = (long)(64 + srA) * ldaB + kbx;
    offB[0] = (long)(((srA >> 5)) * 64 + (srA & 31)) * ldbB + kbx;
    offB[1] = (long)((2 + (srA >> 5)) * 64 + (srA & 31)) * ldbB + kbx;

    const char* Abase = (const char*)(A + (size_t)m0 * ldaE);
    const char* Bbase = (const char*)(Bp + (size_t)n0 * KDIM);

    const int aoff = (wm * 64 + lr) * 128;
    const int boff = (wn * 32 + lr) * 128;
    const int kx0 = (g * 16) ^ ((lr & 7) << 4);
    const int kx1 = (64 + g * 16) ^ ((lr & 7) << 4);

    f4v acc[4][4] = {};
    s8v af[4][2];
    s8v bfr[2][2][2];

#define STG_A1(buf_, kt_) { \
    const char* s0_ = Abase + (long)(kt_) * 2; \
    char* d0_ = smem + ((buf_) * 3) * 16384 + w * 1024; \
    gload16(s0_ + offA[0], d0_); \
    gload16(s0_ + offA[1], d0_ + 8192); }

#define STG_B1(buf_, qn_, kt_) { \
    const char* s0_ = Bbase + (long)(kt_) * 2 + (long)(qn_) * 32 * ldbB; \
    char* d0_ = smem + ((buf_) * 3 + 1 + (qn_)) * 16384 + w * 1024; \
    gload16(s0_ + offB[0], d0_); \
    gload16(s0_ + offB[1], d0_ + 8192); }

#define DS_A1(buf_) { \
    const char* ba_ = smem + ((buf_) * 3) * 16384 + aoff; \
    af[0][0] = *(const s8v*)(ba_ +    0 + kx0); af[0][1] = *(const s8v*)(ba_ +    0 + kx1); \
    af[1][0] = *(const s8v*)(ba_ + 2048 + kx0); af[1][1] = *(const s8v*)(ba_ + 2048 + kx1); \
    af[2][0] = *(const s8v*)(ba_ + 4096 + kx0); af[2][1] = *(const s8v*)(ba_ + 4096 + kx1); \
    af[3][0] = *(const s8v*)(ba_ + 6144 + kx0); af[3][1] = *(const s8v*)(ba_ + 6144 + kx1); }

#define DS_B1(buf_, qn_) { \
    const char* bb_ = smem + ((buf_) * 3 + 1 + (qn_)) * 16384 + boff; \
    bfr[qn_][0][0] = *(const s8v*)(bb_ +    0 + kx0); bfr[qn_][0][1] = *(const s8v*)(bb_ +    0 + kx1); \
    bfr[qn_][1][0] = *(const s8v*)(bb_ + 2048 + kx0); bfr[qn_][1][1] = *(const s8v*)(bb_ + 2048 + kx1); }

#define MM1(fm_, fng_, qn_, kk_) \
    acc[fm_][fng_] = __builtin_amdgcn_mfma_f32_16x16x32_bf16(af[fm_][kk_], bfr[qn_][(fng_)&1][kk_], acc[fm_][fng_], 0, 0, 0);

#define MFMA16_1(qn_, kk_) \
    MM1(0, (qn_)*2+0, qn_, kk_) MM1(0, (qn_)*2+1, qn_, kk_) \
    MM1(1, (qn_)*2+0, qn_, kk_) MM1(1, (qn_)*2+1, qn_, kk_) \
    MM1(2, (qn_)*2+0, qn_, kk_) MM1(2, (qn_)*2+1, qn_, kk_) \
    MM1(3, (qn_)*2+0, qn_, kk_) MM1(3, (qn_)*2+1, qn_, kk_)

#define MFMA32_1(qn_) { MFMA16_1(qn_, 0) MFMA16_1(qn_, 1) }

    STG_A1(0, 0); STG_B1(0, 0, 0); STG_B1(0, 1, 0);
    STG_A1(1, 64); STG_B1(1, 0, 64);
    VM4(); BARX();

    for (int i = 0; i < NITER; ++i) {
        const int t1k = (2 * i + 1) * 64, t2k = (2 * i + 2) * 64, t3k = (2 * i + 3) * 64;
        const bool h2 = (2 * i + 2) < NKT, h3 = (2 * i + 3) < NKT;
        const bool last = (i == NITER - 1);
        DS_A1(0); DS_B1(0, 0); STG_B1(1, 1, t1k);
        BARX(); PRIO1(); MFMA32_1(0); PRIO0(); BARX();
        DS_B1(0, 1); if (h2) { STG_A1(0, t2k); STG_B1(0, 0, t2k); }
        BARX(); PRIO1(); MFMA32_1(1); PRIO0();
        if (last) { VM0(); } else { VM4(); }
        BARX();
        DS_A1(1); DS_B1(1, 0); if (h2) STG_B1(0, 1, t2k);
        BARX(); PRIO1(); MFMA32_1(0); PRIO0(); BARX();
        DS_B1(1, 1); if (h3) { STG_A1(1, t3k); STG_B1(1, 0, t3k); }
        BARX(); PRIO1(); MFMA32_1(1); PRIO0();
        if (last) { VM0(); } else { VM4(); }
        BARX();
    }

    const int jb = m0 % DIM_;   // row offset within batch (MODE 1)
#pragma unroll
    for (int fm = 0; fm < 4; ++fm) {
#pragma unroll
        for (int fng = 0; fng < 4; ++fng) {
            const int col = n0 + wn * 64 + fng * 16 + lr;
#pragma unroll
            for (int r = 0; r < 4; ++r) {
                const int ro = wm * 64 + fm * 16 + g * 4 + r;
                const int row = m0 + ro;
                if (MODE == 0) {
                    Cf[(size_t)row * Nc + col] = acc[fm][fng][r] + bias[col];
                } else {
                    CbO[(size_t)row * Nc + col] =
                        f2bf(acc[fm][fng][r] + addW[(size_t)(jb + ro) * DIM_ + col]);
                }
            }
        }
    }
#undef STG_A1
#undef STG_B1
#undef DS_A1
#undef DS_B1
#undef MM1
#undef MFMA16_1
#undef MFMA32_1
}

// ---------------- reduce_a: alpha partials -> bvecs = Wk_h^T(gq*wk)  (bf16) ----------
__global__ __launch_bounds__(256)
void reduce_a(const float* __restrict__ pv1, const float* __restrict__ pms1,
              const float* __restrict__ Wqkv, const float* __restrict__ w_k,
              unsigned short* __restrict__ bvecs)
{
    const int b = blockIdx.x / H_, h = blockIdx.x % H_;
    const int t = threadIdx.x;
    const int w = t >> 6, l = t & 63;
    __shared__ float Svec[768];
    __shared__ float ew[16];
    __shared__ float Ssh;
    __shared__ float gqwk[64];

    const float* pp = pms1 + (size_t)(b * H_ + h) * 16 * 2;
    float M = pp[0];
    for (int s = 1; s < 16; ++s) M = fmaxf(M, pp[s * 2]);
    if (t < 16) ew[t] = __expf(pp[t * 2] - M);
    __syncthreads();
    if (t == 0) {
        float S = 0.f;
        for (int s = 0; s < 16; ++s) S += ew[s] * pp[s * 2 + 1];
        Ssh = S;
    }
#pragma unroll
    for (int j = 0; j < 3; ++j) {
        const int col = t + j * 256;
        float v = 0.f;
        for (int s = 0; s < 16; ++s)
            v += ew[s] * pv1[((size_t)(b * 16 + s) * 12 + h) * 768 + col];
        Svec[col] = v;
    }
    __syncthreads();

    // gq matvec (Wq rows, coalesced): wave w outputs w*16..+15
    const float invS = 1.f / Ssh;
    for (int i = 0; i < 16; ++i) {
        const int o = w * 16 + i;
        const float* wr = Wqkv + (size_t)(h * 64 + o) * 768;
        float s = 0.f;
#pragma unroll
        for (int j = 0; j < 12; ++j)
            s += wr[l + j * 64] * Svec[l + j * 64];
        s += __shfl_xor(s, 1); s += __shfl_xor(s, 2); s += __shfl_xor(s, 4);
        s += __shfl_xor(s, 8); s += __shfl_xor(s, 16); s += __shfl_xor(s, 32);
        if (l == 0) gqwk[o] = (s * invS) * w_k[h * 64 + o];
    }
    __syncthreads();

    // bvec[d] = sum_c gqwk[c] * Wk[h*64+c][d]   (coalesced over d)
#pragma unroll
    for (int j = 0; j < 3; ++j) {
        const int dcol = t + j * 256;
        float bv = 0.f;
        for (int c = 0; c < 64; ++c)
            bv += gqwk[c] * Wqkv[(size_t)(DIM_ + h * 64 + c) * 768 + dcol];
        bvecs[(size_t)(b * 16 + h) * 768 + dcol] = f2bf(bv);
        if (h < 4) bvecs[(size_t)(b * 16 + 12 + h) * 768 + dcol] = 0;
    }
}

// ---------------- reduce_b: beta partials -> gkv[b*768 + h*64 + o] ----------
__global__ __launch_bounds__(256)
void reduce_b(const float* __restrict__ pv2, const float* __restrict__ pms2,
              const float* __restrict__ Wqkv, float* __restrict__ gkv)
{
    const int b = blockIdx.x / H_, h = blockIdx.x % H_;
    const int t = threadIdx.x;
    const int w = t >> 6, l = t & 63;
    __shared__ float Svec[768];
    __shared__ float ew[16];
    __shared__ float Ssh;

    const float* pp = pms2 + (size_t)(b * H_ + h) * 16 * 2;
    float M = pp[0];
    for (int s = 1; s < 16; ++s) M = fmaxf(M, pp[s * 2]);
    if (t < 16) ew[t] = __expf(pp[t * 2] - M);
    __syncthreads();
    if (t == 0) {
        float S = 0.f;
        for (int s = 0; s < 16; ++s) S += ew[s] * pp[s * 2 + 1];
        Ssh = S;
    }
#pragma unroll
    for (int j = 0; j < 3; ++j) {
        const int col = t + j * 256;
        float v = 0.f;
        for (int s = 0; s < 16; ++s)
            v += ew[s] * pv2[((size_t)(b * 16 + s) * 12 + h) * 768 + col];
        Svec[col] = v;
    }
    __syncthreads();

    // gk matvec (Wk rows, coalesced)
    const float invS = 1.f / Ssh;
    for (int i = 0; i < 16; ++i) {
        const int o = w * 16 + i;
        const float* wr = Wqkv + (size_t)(DIM_ + h * 64 + o) * 768;
        float s = 0.f;
#pragma unroll
        for (int j = 0; j < 12; ++j)
            s += wr[l + j * 64] * Svec[l + j * 64];
        s += __shfl_xor(s, 1); s += __shfl_xor(s, 2); s += __shfl_xor(s, 4);
        s += __shfl_xor(s, 8); s += __shfl_xor(s, 16); s += __shfl_xor(s, 32);
        if (l == 0) gkv[(size_t)b * DIM_ + h * 64 + o] = s * invS;
    }
}

// ---------------- avec_prep: avec[h][d] = sum_c w_q[h,c] Wq[h*64+c][d] (bf16) -------
__global__ __launch_bounds__(256)
void avec_prep(const float* __restrict__ Wqkv, const float* __restrict__ w_q,
               unsigned short* __restrict__ avecb)
{
    const int h = blockIdx.x;
    const int t = threadIdx.x;
    if (h >= H_) {
#pragma unroll
        for (int j = 0; j < 3; ++j) avecb[(size_t)h * 768 + t + j * 256] = 0;
        return;
    }
    __shared__ float wl[64];
    if (t < 64) wl[t] = w_q[h * 64 + t];
    __syncthreads();
#pragma unroll
    for (int j = 0; j < 3; ++j) {
        const int dcol = t + j * 256;
        float a = 0.f;
        for (int c = 0; c < 64; ++c)
            a += wl[c] * Wqkv[(size_t)(h * 64 + c) * 768 + dcol];
        avecb[(size_t)h * 768 + dcol] = f2bf(a);
    }
}

// ---------------- conversion: x -> xb, Wv -> wvT (transposed) ----------
__global__ void cvt_all(const float* __restrict__ x, const float* __restrict__ Wqkv,
                        unsigned short* __restrict__ xb, unsigned short* __restrict__ wvT,
                        int n4x)
{
    int i = blockIdx.x * 256 + threadIdx.x;
    if (i < n4x) {
        float4 v = ((const float4*)x)[i];
        ushort4 o;
        o.x = f2bf(v.x); o.y = f2bf(v.y); o.z = f2bf(v.z); o.w = f2bf(v.w);
        ((ushort4*)xb)[i] = o;
    } else {
        const int k = i - n4x;
        const int ii = k % DIM_;
        const int c0 = (k / DIM_) * 4;
        ushort4 o;
        o.x = f2bf(Wqkv[(size_t)(2 * DIM_ + c0 + 0) * DIM_ + ii]);
        o.y = f2bf(Wqkv[(size_t)(2 * DIM_ + c0 + 1) * DIM_ + ii]);
        o.z = f2bf(Wqkv[(size_t)(2 * DIM_ + c0 + 2) * DIM_ + ii]);
        o.w = f2bf(Wqkv[(size_t)(2 * DIM_ + c0 + 3) * DIM_ + ii]);
        *(ushort4*)&wvT[(size_t)ii * DIM_ + c0] = o;
    }
}

// ---------------- fold gk into Wp: W2[b][j][c] = bf16(Wp[j][c] * gk[b*768+c]) --------
__global__ __launch_bounds__(256)
void fold_wp(const float* __restrict__ Wp, const float* __restrict__ gk,
             unsigned short* __restrict__ W2)
{
    int idx = blockIdx.x * 256 + threadIdx.x;
    int e4 = idx * 4;
    int b = (int)((unsigned)e4 / (unsigned)(DIM_ * DIM_));
    int rem = e4 - b * (DIM_ * DIM_);
    int c = rem % DIM_;
    float4 wv = *(const float4*)&Wp[rem];
    const float* gp = &gk[b * DIM_ + c];
    ushort4 o;
    o.x = f2bf(wv.x * gp[0]); o.y = f2bf(wv.y * gp[1]);
    o.z = f2bf(wv.z * gp[2]); o.w = f2bf(wv.w * gp[3]);
    *(ushort4*)&W2[e4] = o;
}

extern "C" void kernel_launch(void* const* d_in, const int* in_sizes, int n_in,
                              void* d_out, int out_size, void* d_ws, size_t ws_size,
                              hipStream_t stream)
{
    const float* x    = (const float*)d_in[0];
    const float* Wqkv = (const float*)d_in[1];
    const float* Wp   = (const float*)d_in[2];
    const float* bp   = (const float*)d_in[3];
    const float* w_q  = (const float*)d_in[4];
    const float* w_k  = (const float*)d_in[5];
    float* out = (float*)d_out;

    constexpr size_t NXB = (size_t)M_ * DIM_;
    constexpr size_t NWV = (size_t)DIM_ * DIM_;
    constexpr size_t NW2 = (size_t)B_ * DIM_ * DIM_;

    char* p = (char*)d_ws;
    unsigned short* xb    = (unsigned short*)p; p += NXB * 2;
    unsigned short* wvT   = (unsigned short*)p; p += NWV * 2;
    unsigned short* w2b   = (unsigned short*)p; p += NW2 * 2;
    unsigned short* w4b   = (unsigned short*)p; p += NW2 * 2;
    unsigned short* avecb = (unsigned short*)p; p += (size_t)16 * 768 * 2;
    unsigned short* bvecs = (unsigned short*)p; p += (size_t)B_ * 16 * 768 * 2;
    float* pv1  = (float*)p; p += (size_t)B_ * 16 * 12 * 768 * 4;
    float* pms1 = (float*)p; p += (size_t)B_ * H_ * 16 * 2 * 4;
    float* pv2  = (float*)p; p += (size_t)B_ * 16 * 12 * 768 * 4;
    float* pms2 = (float*)p; p += (size_t)B_ * H_ * 16 * 2 * 4;
    float* gkv  = (float*)p; p += (size_t)B_ * DIM_ * 4;

    // 1) convert x (bf16) + Wv^T (bf16)
    constexpr int N4X  = (int)(NXB / 4);
    constexpr int NTOT = N4X + (int)(NWV / 4);
    cvt_all<<<NTOT / 256, 256, 0, stream>>>(x, Wqkv, xb, wvT, N4X);

    // 2) avec[h] = Wq_h^T w_q_h  (bf16 [16][768], zeros h>=12)
    avec_prep<<<16, 256, 0, stream>>>(Wqkv, w_q, avecb);

    // 3) alpha score pass  (128 blocks)
    score_pass<0><<<128, 512, 0, stream>>>(xb, avecb, pv1, pms1);

    // 4) alpha reduce -> bvecs = Wk_h^T(gq*wk)  (bf16 [B][16][768])
    reduce_a<<<B_ * H_, 256, 0, stream>>>(pv1, pms1, Wqkv, w_k, bvecs);

    // 5) beta score pass  (128 blocks)
    score_pass<1><<<128, 512, 0, stream>>>(xb, bvecs, pv2, pms2);

    // 6) beta reduce -> gkv = global_k
    reduce_b<<<B_ * H_, 256, 0, stream>>>(pv2, pms2, Wqkv, gkv);

    // 7) W2[b] = Wp * gk_b (bf16)
    fold_wp<<<(int)(NW2 / 4 / 256), 256, 0, stream>>>(Wp, gkv, w2b);

    // 8) W4 = W2 @ Wv + Wq  (flat [6144,768] GEMM, 144 blocks)
    gemm128<1><<<48 * 3, 512, 0, stream>>>(w2b, DIM_, wvT, nullptr, w4b, nullptr, Wqkv,
                                           DIM_, 3);

    // 9) out = x @ W4_b^T + bp   (768 blocks)
    gemm128<0><<<256 * 3, 512, 0, stream>>>(xb, DIM_, w4b, out, nullptr, bp, nullptr,
                                            DIM_, 3);
}